// Round 8
// baseline (631.721 us; speedup 1.0000x reference)
//
#include <hip/hip_runtime.h>
#include <hip/hip_bf16.h>
#include <cstddef>
#include <cstdint>

#define NM 50000
#define NA 50000
#define ND 500
#define FEAT 128
#define KDIM 768
#define BATCH 1024
#define NEDGE 1600000
#define MD 128            // ELL row capacity (deg ~ Poisson(32); P(>128) ~ 1e-38)

typedef __bf16 bf16_t;
typedef bf16_t bf16x8 __attribute__((ext_vector_type(8)));
typedef bf16_t bf16x2 __attribute__((ext_vector_type(2)));
typedef float f32x4 __attribute__((ext_vector_type(4)));
typedef unsigned short u16;

__device__ __forceinline__ float sigf(float x) { return 1.0f / (1.0f + __expf(-x)); }

// ---------------- ELL fill, TRANSPOSED planes (rank-major) --------------------
// Write adjT[rank][node]: active write set at any instant is ~5 rank-planes
// (~125KB per XCD slice) -> lines stay L2-resident until dense-filled (kills
// the 5x partial-line write amplification of node-major ELL).
// blockIdx&7 ~ XCD owns 1/8 node range; rank trick: atomicAdd returns rank.
__global__ __launch_bounds__(256) void fill_ellT(
    const int* __restrict__ src, const int* __restrict__ dst,
    int* __restrict__ cnt_m, int* __restrict__ cnt_a,
    u16* __restrict__ adjTm, u16* __restrict__ adjTa)
{
  const int x = blockIdx.x & 7;
  const int grp = blockIdx.x >> 3;            // 0..255
  const int mlo = x * (NM / 8), mhi = mlo + (NM / 8);
  const int alo = x * (NA / 8), ahi = alo + (NA / 8);
  const int ebase = grp * (NEDGE / 256);
  const int eend = ebase + (NEDGE / 256);
  for (int e = ebase + threadIdx.x; e < eend; e += 256) {
    int s = __builtin_nontemporal_load(&src[e]);
    int d = __builtin_nontemporal_load(&dst[e]);
    if (s >= mlo && s < mhi) {
      int r = atomicAdd(&cnt_m[s], 1);
      if (r < MD) adjTm[(size_t)r * NM + s] = (u16)d;
    }
    if (d >= alo && d < ahi) {
      int r = atomicAdd(&cnt_a[d], 1);
      if (r < MD) adjTa[(size_t)d - 0 + (size_t)r * NA] = (u16)s;
    }
  }
}

// ---------------- transpose adjT[rank][node] -> adj[node][rank] ---------------
// LDS-tiled 64x64 u16; both global phases coalesced (128B runs).
__global__ __launch_bounds__(256) void transp_kernel(
    const u16* __restrict__ adjTm, const u16* __restrict__ adjTa,
    u16* __restrict__ adjm, u16* __restrict__ adja)
{
  __shared__ u16 tile[64][68];
  const int s0 = blockIdx.x * 64;
  const int r0 = blockIdx.y * 64;
  const u16* T = blockIdx.z ? adjTa : adjTm;
  u16* A = blockIdx.z ? adja : adjm;
  for (int e = threadIdx.x; e < 4096; e += 256) {
    int rr = e >> 6, cc = e & 63;
    int s = s0 + cc;
    tile[rr][cc] = (s < NM) ? T[(size_t)(r0 + rr) * NM + s] : (u16)0;
  }
  __syncthreads();
  for (int e = threadIdx.x; e < 4096; e += 256) {
    int nn = e >> 6, rk = e & 63;
    int s = s0 + nn;
    if (s < NM) A[(size_t)s * MD + r0 + rk] = tile[rk][nn];
  }
}

// ---------------- util: 4x weight transpose->bf16 + deg->dinv ----------------
__global__ __launch_bounds__(256) void util_kernel(
    const float* __restrict__ W0, const float* __restrict__ W1,
    const float* __restrict__ W2, const float* __restrict__ W3,
    bf16_t* __restrict__ T0, bf16_t* __restrict__ T1,
    bf16_t* __restrict__ T2, bf16_t* __restrict__ T3,
    const int* __restrict__ cnt_m, const int* __restrict__ cnt_a,
    float* __restrict__ dm, float* __restrict__ da)
{
  const int b = blockIdx.x;
  if (b < 512) {
    const float* W = (b < 128) ? W0 : (b < 256) ? W1 : (b < 384) ? W2 : W3;
    bf16_t* T      = (b < 128) ? T0 : (b < 256) ? T1 : (b < 384) ? T2 : T3;
    int c = b & 127;
    for (int k = threadIdx.x; k < KDIM; k += 256)
      T[(size_t)c * KDIM + k] = (bf16_t)W[(size_t)k * FEAT + c];
  } else {
    int i = (b - 512) * 256 + threadIdx.x;
    if (i < NM) { int c = cnt_m[i]; dm[i] = c > 0 ? rsqrtf((float)c) : 0.f; }
    if (i < NA) { int c = cnt_a[i]; da[i] = c > 0 ? rsqrtf((float)c) : 0.f; }
  }
}

// ---------------- projection body: C = sigmoid(A[M,768] @ W + b) -------------
template<bool BF16OUT>
__device__ __forceinline__ void proj_body(
    const float* __restrict__ A, const bf16_t* __restrict__ Wt,
    const float* __restrict__ bias, void* __restrict__ Cout, int M, int rowBase,
    const float* __restrict__ rowscale, float* __restrict__ C2)
{
  __shared__ bf16x8 sm[1024];  // [0..511]=A frags, [512..1023]=B frags
  const int tid = threadIdx.x;
  const int lane = tid & 63;
  const int wid = tid >> 6;

  f32x4 acc[4][4];
  #pragma unroll
  for (int m = 0; m < 4; ++m)
    #pragma unroll
    for (int n = 0; n < 4; ++n)
      acc[m][n] = (f32x4){0.f, 0.f, 0.f, 0.f};

  const int rl0 = ((tid >> 6) << 4) + (tid & 15);
  const int k8 = (tid >> 4) & 3;

  for (int k0 = 0; k0 < KDIM; k0 += 32) {
    #pragma unroll
    for (int i = 0; i < 2; ++i) {
      int rloc = rl0 + 64 * i;
      int rg = rowBase + rloc;
      if (rg > M - 1) rg = M - 1;
      const float* ap = A + (size_t)rg * KDIM + k0 + k8 * 8;
      float4 v0 = *(const float4*)ap;
      float4 v1 = *(const float4*)(ap + 4);
      bf16x8 w;
      w[0] = (bf16_t)v0.x; w[1] = (bf16_t)v0.y; w[2] = (bf16_t)v0.z; w[3] = (bf16_t)v0.w;
      w[4] = (bf16_t)v1.x; w[5] = (bf16_t)v1.y; w[6] = (bf16_t)v1.z; w[7] = (bf16_t)v1.w;
      sm[tid + i * 256] = w;
      sm[512 + tid + i * 256] = *(const bf16x8*)(Wt + (size_t)rloc * KDIM + k0 + k8 * 8);
    }
    __syncthreads();
    bf16x8 a[4], b[4];
    const int fm = (wid >> 1) * 4, fn = (wid & 1) * 4;
    #pragma unroll
    for (int m = 0; m < 4; ++m) a[m] = sm[(fm + m) * 64 + lane];
    #pragma unroll
    for (int n = 0; n < 4; ++n) b[n] = sm[512 + (fn + n) * 64 + lane];
    #pragma unroll
    for (int m = 0; m < 4; ++m)
      #pragma unroll
      for (int n = 0; n < 4; ++n)
        acc[m][n] = __builtin_amdgcn_mfma_f32_16x16x32_bf16(a[m], b[n], acc[m][n], 0, 0, 0);
    __syncthreads();
  }

  // C frag layout: col=lane&15, row=(lane>>4)*4+reg
  const int wRow = (wid >> 1) * 64, wCol = (wid & 1) * 64;
  const int r0 = (lane >> 4) * 4, cc = lane & 15;
  #pragma unroll
  for (int n = 0; n < 4; ++n) {
    int col = wCol + n * 16 + cc;
    float bb = bias[col];
    #pragma unroll
    for (int m = 0; m < 4; ++m) {
      #pragma unroll
      for (int r = 0; r < 4; ++r) {
        int row = rowBase + wRow + m * 16 + r0 + r;
        if (row < M) {
          float v = sigf(acc[m][n][r] + bb);
          float sc = rowscale ? rowscale[row] : 1.0f;
          if constexpr (BF16OUT)
            ((bf16_t*)Cout)[(size_t)row * FEAT + col] = (bf16_t)(v * sc);
          else
            ((float*)Cout)[(size_t)row * FEAT + col] = v * sc;
          if (C2) C2[(size_t)row * FEAT + col] = 0.25f * v;
        }
      }
    }
  }
}

template<bool BF16OUT>
__global__ __launch_bounds__(256) void proj_mfma(
    const float* __restrict__ A, const bf16_t* __restrict__ Wt,
    const float* __restrict__ bias, void* __restrict__ Cout, int M,
    const float* __restrict__ rowscale, float* __restrict__ C2)
{
  proj_body<BF16OUT>(A, Wt, bias, Cout, M, blockIdx.x * 128, rowscale, C2);
}

// fused small projections: vmi (8 blocks), vkey (4), vval (4)
__global__ __launch_bounds__(256) void proj3_kernel(
    const float* __restrict__ x, const float* __restrict__ domain,
    const bf16_t* __restrict__ t0, const bf16_t* __restrict__ t1,
    const bf16_t* __restrict__ t2,
    const float* __restrict__ bsde, const float* __restrict__ bkey,
    const float* __restrict__ bval,
    float* __restrict__ vmi, float* __restrict__ vkey, float* __restrict__ vval)
{
  const int b = blockIdx.x;
  if (b < 8)       proj_body<false>(x, t0, bsde, vmi, BATCH, b * 128, nullptr, nullptr);
  else if (b < 12) proj_body<false>(domain, t1, bkey, vkey, ND, (b - 8) * 128, nullptr, nullptr);
  else             proj_body<false>(domain, t2, bval, vval, ND, (b - 12) * 128, nullptr, nullptr);
}

// ---------------- attention ----------------
__global__ __launch_bounds__(256) void attn_kernel(
    const float* __restrict__ vmi, const float* __restrict__ vkey,
    const float* __restrict__ vval, bf16_t* __restrict__ zm)
{
  const int i = blockIdx.x;
  const int tid = threadIdx.x;
  __shared__ float vs[FEAT];
  __shared__ float al[ND];
  __shared__ float red[4];
  __shared__ float totS;
  if (tid < FEAT) vs[tid] = vmi[(size_t)i * FEAT + tid];
  __syncthreads();
  float part = 0.f;
  for (int j = tid; j < ND; j += 256) {
    const float* kr = vkey + (size_t)j * FEAT;
    float dot = 0.f;
    #pragma unroll 8
    for (int k = 0; k < FEAT; k += 4) {
      float4 kv = *(const float4*)(kr + k);
      dot += vs[k] * kv.x + vs[k + 1] * kv.y + vs[k + 2] * kv.z + vs[k + 3] * kv.w;
    }
    al[j] = dot;
    part += dot;
  }
  #pragma unroll
  for (int o = 32; o > 0; o >>= 1) part += __shfl_down(part, o, 64);
  if ((tid & 63) == 0) red[tid >> 6] = part;
  __syncthreads();
  if (tid == 0) totS = red[0] + red[1] + red[2] + red[3];
  __syncthreads();
  const float inv = 1.0f / totS;
  if (tid < FEAT) {
    float s = 0.f;
    #pragma unroll 4
    for (int j = 0; j < ND; ++j) s += al[j] * vval[(size_t)j * FEAT + tid];
    float z = 0.5f * (s * inv + vs[tid]);
    zm[(size_t)i * FEAT + tid] = (bf16_t)z;
  }
}

// ---------------- row-gather: sum n bf16 rows of ELL list (dword per lane) ----
// 16-deep batches for memory-level parallelism.
__device__ __forceinline__ void gatherE(const uint32_t* __restrict__ base,
                                        const u16* __restrict__ row, int n,
                                        float& ax, float& ay)
{
  float lax = 0.f, lay = 0.f;
  int j = 0;
  while (j + 16 <= n) {
    int u[16];
    #pragma unroll
    for (int q = 0; q < 16; ++q) u[q] = row[j + q];
    uint32_t w[16];
    #pragma unroll
    for (int q = 0; q < 16; ++q) w[q] = base[(size_t)u[q] * 64];
    #pragma unroll
    for (int q = 0; q < 16; ++q) {
      lax += __uint_as_float(w[q] << 16);
      lay += __uint_as_float(w[q] & 0xffff0000u);
    }
    j += 16;
  }
  while (j + 4 <= n) {
    int u[4];
    #pragma unroll
    for (int q = 0; q < 4; ++q) u[q] = row[j + q];
    uint32_t w[4];
    #pragma unroll
    for (int q = 0; q < 4; ++q) w[q] = base[(size_t)u[q] * 64];
    #pragma unroll
    for (int q = 0; q < 4; ++q) {
      lax += __uint_as_float(w[q] << 16);
      lay += __uint_as_float(w[q] & 0xffff0000u);
    }
    j += 4;
  }
  while (j < n) {
    int u = row[j];
    uint32_t w = base[(size_t)u * 64];
    lax += __uint_as_float(w << 16);
    lay += __uint_as_float(w & 0xffff0000u);
    ++j;
  }
  ax = lax; ay = lay;
}

// ---- pass1 (api side): y01a = y0a + dinv_a^2 * sum_{m in N(a)} M0y[m] --------
__global__ __launch_bounds__(256) void prop_pass1(
    const bf16_t* __restrict__ M0y, const bf16_t* __restrict__ y0a,
    bf16_t* __restrict__ y01a,
    const u16* __restrict__ adja, const int* __restrict__ cnt_a,
    const float* __restrict__ da)
{
  const int a = blockIdx.x * 4 + (threadIdx.x >> 6);
  const int lane = threadIdx.x & 63;
  int n = cnt_a[a]; if (n > MD) n = MD;
  float ax, ay;
  gatherE((const uint32_t*)M0y + lane, adja + (size_t)a * MD, n, ax, ay);
  const float d = da[a];
  const float s2 = d * d;
  uint32_t y0 = ((const uint32_t*)y0a)[(size_t)a * 64 + lane];
  bf16x2 pk;
  pk[0] = (bf16_t)(__uint_as_float(y0 << 16) + s2 * ax);
  pk[1] = (bf16_t)(__uint_as_float(y0 & 0xffff0000u) + s2 * ay);
  *(bf16x2*)(y01a + (size_t)a * FEAT + 2 * lane) = pk;
}

// ---- pass2 (mashup side): Sy = M0y + dinv_m^2 * sum_{a in N(m)} y01a[a] ------
__global__ __launch_bounds__(256) void prop_pass2(
    const bf16_t* __restrict__ y01a, const bf16_t* __restrict__ M0y,
    bf16_t* __restrict__ Sy,
    const u16* __restrict__ adjm, const int* __restrict__ cnt_m,
    const float* __restrict__ dm)
{
  const int m = blockIdx.x * 4 + (threadIdx.x >> 6);
  const int lane = threadIdx.x & 63;
  int n = cnt_m[m]; if (n > MD) n = MD;
  float ax, ay;
  gatherE((const uint32_t*)y01a + lane, adjm + (size_t)m * MD, n, ax, ay);
  const float d = dm[m];
  const float s2 = d * d;
  uint32_t m0 = ((const uint32_t*)M0y)[(size_t)m * 64 + lane];
  bf16x2 pk;
  pk[0] = (bf16_t)(__uint_as_float(m0 << 16) + s2 * ax);
  pk[1] = (bf16_t)(__uint_as_float(m0 & 0xffff0000u) + s2 * ay);
  *(bf16x2*)(Sy + (size_t)m * FEAT + 2 * lane) = pk;
}

// ---- pass3 (api side): O = 0.25*A0 + 0.25*dinv_a * sum_{m in N(a)} Sy[m] -----
__global__ __launch_bounds__(256) void prop_pass3(
    const bf16_t* __restrict__ Sy, const float* __restrict__ outA,
    bf16_t* __restrict__ Obf,
    const u16* __restrict__ adja, const int* __restrict__ cnt_a,
    const float* __restrict__ da)
{
  const int a = blockIdx.x * 4 + (threadIdx.x >> 6);
  const int lane = threadIdx.x & 63;
  int n = cnt_a[a]; if (n > MD) n = MD;
  float ax, ay;
  gatherE((const uint32_t*)Sy + lane, adja + (size_t)a * MD, n, ax, ay);
  const float q = 0.25f * da[a];
  const float2 prev = *(const float2*)(outA + (size_t)a * FEAT + 2 * lane);
  bf16x2 pk;
  pk[0] = (bf16_t)(prev.x + q * ax);
  pk[1] = (bf16_t)(prev.y + q * ay);
  *(bf16x2*)(Obf + (size_t)a * FEAT + 2 * lane) = pk;
}

// ---------------- pred = Z[1024,128] @ O[50000,128]^T, bf16 MFMA --------------
__global__ __launch_bounds__(256) void pred_mfma(
    const bf16_t* __restrict__ Z, const bf16_t* __restrict__ O,
    float* __restrict__ out)
{
  const int lane = threadIdx.x & 63;
  const int wid = threadIdx.x >> 6;
  const int nBase = blockIdx.x * 256 + wid * 64;
  const int cc = lane & 15;
  const int kOff = (lane >> 4) * 8;

  bf16x8 b[4][4];
  #pragma unroll
  for (int n = 0; n < 4; ++n) {
    int c = nBase + n * 16 + cc;
    if (c > NA - 1) c = NA - 1;
    #pragma unroll
    for (int kk = 0; kk < 4; ++kk)
      b[n][kk] = *(const bf16x8*)(O + (size_t)c * FEAT + kk * 32 + kOff);
  }

  const int r0 = (lane >> 4) * 4;
  #pragma unroll
  for (int it = 0; it < 4; ++it) {
    const int iBase = blockIdx.y * 256 + it * 64;
    f32x4 acc[4][4];
    #pragma unroll
    for (int m = 0; m < 4; ++m)
      #pragma unroll
      for (int n = 0; n < 4; ++n)
        acc[m][n] = (f32x4){0.f, 0.f, 0.f, 0.f};

    #pragma unroll
    for (int kk = 0; kk < 4; ++kk) {
      bf16x8 a[4];
      #pragma unroll
      for (int m = 0; m < 4; ++m)
        a[m] = *(const bf16x8*)(Z + (size_t)(iBase + cc + m * 16) * FEAT + kk * 32 + kOff);
      #pragma unroll
      for (int m = 0; m < 4; ++m)
        #pragma unroll
        for (int n = 0; n < 4; ++n)
          acc[m][n] = __builtin_amdgcn_mfma_f32_16x16x32_bf16(a[m], b[n][kk], acc[m][n], 0, 0, 0);
    }

    #pragma unroll
    for (int n = 0; n < 4; ++n) {
      int col = nBase + n * 16 + cc;
      if (col < NA) {
        #pragma unroll
        for (int m = 0; m < 4; ++m) {
          #pragma unroll
          for (int r = 0; r < 4; ++r) {
            int row = iBase + m * 16 + r0 + r;
            __builtin_nontemporal_store(acc[m][n][r], &out[(size_t)row * NA + col]);
          }
        }
      }
    }
  }
}

static inline char* alignup(char* p, size_t a) {
  return (char*)(((uintptr_t)p + a - 1) & ~(uintptr_t)(a - 1));
}

extern "C" void kernel_launch(void* const* d_in, const int* in_sizes, int n_in,
                              void* d_out, int out_size, void* d_ws, size_t ws_size,
                              hipStream_t stream) {
  const float* x      = (const float*)d_in[0];
  const float* mashup = (const float*)d_in[1];
  const float* domain = (const float*)d_in[2];
  const float* api    = (const float*)d_in[3];
  const float* Wsde   = (const float*)d_in[4];
  const float* bsde   = (const float*)d_in[5];
  const float* Wval   = (const float*)d_in[6];
  const float* bval   = (const float*)d_in[7];
  const float* Wkey   = (const float*)d_in[8];
  const float* bkey   = (const float*)d_in[9];
  const float* Wsie   = (const float*)d_in[10];
  const float* bsie   = (const float*)d_in[11];
  const int* esrc     = (const int*)d_in[12];
  const int* edst     = (const int*)d_in[13];
  float* out = (float*)d_out;

  // workspace layout (~118 MB)
  char* p = (char*)d_ws;
  bf16_t* M0y  = (bf16_t*)p; p += (size_t)NM * FEAT * 2;          // 12.8MB
  bf16_t* y0a  = (bf16_t*)p; p += (size_t)NA * FEAT * 2;          // 12.8MB
  bf16_t* y01a = (bf16_t*)p; p += (size_t)NA * FEAT * 2;          // 12.8MB
  bf16_t* Sy   = (bf16_t*)p; p += (size_t)NM * FEAT * 2;          // 12.8MB
  float*  outA = (float*)p;  p += (size_t)NA * FEAT * 4;          // 25.6MB
  bf16_t* Obf  = (bf16_t*)p; p += (size_t)NA * FEAT * 2;          // 12.8MB
  u16*    adjm = (u16*)p;    p += (size_t)NM * MD * 2;            // 12.8MB
  u16*    adja = (u16*)p;    p += (size_t)NA * MD * 2;            // 12.8MB
  float*  vmi  = (float*)p;  p += (size_t)BATCH * FEAT * 4;
  float*  vkey = (float*)p;  p += (size_t)ND * FEAT * 4;
  float*  vval = (float*)p;  p += (size_t)ND * FEAT * 4;
  bf16_t* zm   = (bf16_t*)p; p += (size_t)BATCH * FEAT * 2;
  int* cnt_m = (int*)p; p += (size_t)NM * 4;                      // contiguous with
  int* cnt_a = (int*)p; p += (size_t)NA * 4;                      // cnt_m (one memset)
  float* dm  = (float*)p; p += (size_t)NM * 4;
  float* da  = (float*)p; p += (size_t)NA * 4;
  p = alignup(p, 16);
  bf16_t* wt0 = (bf16_t*)p; p += (size_t)FEAT * KDIM * 2;
  bf16_t* wt1 = (bf16_t*)p; p += (size_t)FEAT * KDIM * 2;
  bf16_t* wt2 = (bf16_t*)p; p += (size_t)FEAT * KDIM * 2;
  bf16_t* wt3 = (bf16_t*)p; p += (size_t)FEAT * KDIM * 2;
  // adjT (rank-major, 12.8MB each) overlays M0y/y0a: dead once transp finishes,
  // which is before proj_mfma writes M0y/y0a (same stream, sequential).
  u16* adjTm = (u16*)M0y;
  u16* adjTa = (u16*)y0a;

  hipMemsetAsync(cnt_m, 0, (size_t)(NM + NA) * sizeof(int), stream);

  // ---- build (transposed ELL, rank trick) ----
  fill_ellT<<<2048, 256, 0, stream>>>(esrc, edst, cnt_m, cnt_a, adjTm, adjTa);
  transp_kernel<<<dim3((NM + 63) / 64, MD / 64, 2), 256, 0, stream>>>(
      adjTm, adjTa, adjm, adja);
  util_kernel<<<512 + (NM + 255) / 256, 256, 0, stream>>>(
      Wsde, Wkey, Wval, Wsie, wt0, wt1, wt2, wt3, cnt_m, cnt_a, dm, da);

  // ---- projections ----
  proj3_kernel<<<16, 256, 0, stream>>>(x, domain, wt0, wt1, wt2,
                                       bsde, bkey, bval, vmi, vkey, vval);
  attn_kernel<<<BATCH, 256, 0, stream>>>(vmi, vkey, vval, zm);

  // mashup: M0y = dm[m]*sigmoid(...); api: y0a = da[a]*sigmoid(...), outA = 0.25*sig
  proj_mfma<true><<<(NM + 127) / 128, 256, 0, stream>>>(mashup, wt0, bsde, M0y, NM,
                                                        dm, nullptr);
  proj_mfma<true><<<(NA + 127) / 128, 256, 0, stream>>>(api, wt3, bsie, y0a, NA,
                                                        da, outA);

  // ---- bipartite LightGCN: out_api = 0.25*(A0 + P^T(M0+M1+M2)) ----
  prop_pass1<<<NA / 4, 256, 0, stream>>>(M0y, y0a, y01a, adja, cnt_a, da);
  prop_pass2<<<NM / 4, 256, 0, stream>>>(y01a, M0y, Sy, adjm, cnt_m, dm);
  prop_pass3<<<NA / 4, 256, 0, stream>>>(Sy, outA, Obf, adja, cnt_a, da);

  pred_mfma<<<dim3((NA + 255) / 256, BATCH / 256), 256, 0, stream>>>(zm, Obf, out);
}

// Round 9
// 549.326 us; speedup vs baseline: 1.1500x; 1.1500x over previous
//
#include <hip/hip_runtime.h>
#include <hip/hip_bf16.h>
#include <cstddef>
#include <cstdint>

#define NM 50000
#define NA 50000
#define ND 500
#define FEAT 128
#define KDIM 768
#define BATCH 1024
#define NEDGE 1600000
#define MD 128            // ELL row capacity (deg ~ Poisson(32); P(>128) ~ 1e-38)

#define NBIN 196          // ceil(50000/256) node bins of 256 nodes
#define CAP 10240         // records per bin (expected 8163, 23 sigma headroom)
#define F1B 400           // fill_bin blocks
#define F1E (NEDGE / F1B) // 4000 edges per block (exact)

typedef __bf16 bf16_t;
typedef bf16_t bf16x8 __attribute__((ext_vector_type(8)));
typedef bf16_t bf16x2 __attribute__((ext_vector_type(2)));
typedef float f32x4 __attribute__((ext_vector_type(4)));
typedef unsigned short u16;

__device__ __forceinline__ float sigf(float x) { return 1.0f / (1.0f + __expf(-x)); }

// ---------------- fill pass 1: edges -> bin-bucketed packed records -----------
// LDS histogram per 256-node bin (both sides), ONE global atomic per
// (block,bin) run reservation (<=157K global atomics vs 3.2M per-edge),
// then emit (node<<16|neighbor) records into the reserved contiguous runs.
__global__ __launch_bounds__(256) void fill_bin(
    const int* __restrict__ src, const int* __restrict__ dst,
    int* __restrict__ bcur, uint32_t* __restrict__ rec /* [2*NBIN][CAP] */)
{
  __shared__ int hist[2 * NBIN];
  __shared__ int base[2 * NBIN];
  const int tid = threadIdx.x;
  for (int i = tid; i < 2 * NBIN; i += 256) hist[i] = 0;
  __syncthreads();
  const int e0 = blockIdx.x * F1E;
  for (int i = tid; i < F1E; i += 256) {
    int s = __builtin_nontemporal_load(&src[e0 + i]);
    int d = __builtin_nontemporal_load(&dst[e0 + i]);
    atomicAdd(&hist[s >> 8], 1);
    atomicAdd(&hist[NBIN + (d >> 8)], 1);
  }
  __syncthreads();
  for (int i = tid; i < 2 * NBIN; i += 256) {
    int c = hist[i];
    base[i] = c ? atomicAdd(&bcur[i], c) : 0;
    hist[i] = 0;  // reuse as emit cursor
  }
  __syncthreads();
  for (int i = tid; i < F1E; i += 256) {
    int s = __builtin_nontemporal_load(&src[e0 + i]);
    int d = __builtin_nontemporal_load(&dst[e0 + i]);
    int bm = s >> 8, ba = NBIN + (d >> 8);
    int rm = base[bm] + atomicAdd(&hist[bm], 1);
    int ra = base[ba] + atomicAdd(&hist[ba], 1);
    if (rm < CAP) rec[(size_t)bm * CAP + rm] = ((uint32_t)s << 16) | (uint32_t)d;
    if (ra < CAP) rec[(size_t)ba * CAP + ra] = ((uint32_t)d << 16) | (uint32_t)s;
  }
}

// ---------------- fill pass 2: records -> ELL rows + exact degrees ------------
// One block per (bin,side): private 64KB adj window (line-local dense writes),
// ranks via LDS counters, degrees written non-atomically (owner-exclusive).
__global__ __launch_bounds__(256) void fill_ell2(
    const uint32_t* __restrict__ rec, const int* __restrict__ bcur,
    u16* __restrict__ adjm, u16* __restrict__ adja,
    int* __restrict__ cnt_m, int* __restrict__ cnt_a)
{
  __shared__ int cnt256[256];
  const int g = blockIdx.x;                 // 0..2*NBIN-1
  const int side = g >= NBIN;
  const int bin = side ? g - NBIN : g;
  u16* adj = side ? adja : adjm;
  int* cnt = side ? cnt_a : cnt_m;
  cnt256[threadIdx.x] = 0;
  __syncthreads();
  int n = bcur[g]; if (n > CAP) n = CAP;
  const uint32_t* rb = rec + (size_t)g * CAP;
  for (int i = threadIdx.x; i < n; i += 256) {
    uint32_t r = rb[i];
    int node = (int)(r >> 16);
    int rk = atomicAdd(&cnt256[node & 255], 1);
    if (rk < MD) adj[(size_t)node * MD + rk] = (u16)(r & 0xffffu);
  }
  __syncthreads();
  int node = bin * 256 + threadIdx.x;
  if (node < NM) cnt[node] = cnt256[threadIdx.x];
}

// ---------------- util: 4x weight transpose->bf16 + deg->dinv ----------------
__global__ __launch_bounds__(256) void util_kernel(
    const float* __restrict__ W0, const float* __restrict__ W1,
    const float* __restrict__ W2, const float* __restrict__ W3,
    bf16_t* __restrict__ T0, bf16_t* __restrict__ T1,
    bf16_t* __restrict__ T2, bf16_t* __restrict__ T3,
    const int* __restrict__ cnt_m, const int* __restrict__ cnt_a,
    float* __restrict__ dm, float* __restrict__ da)
{
  const int b = blockIdx.x;
  if (b < 512) {
    const float* W = (b < 128) ? W0 : (b < 256) ? W1 : (b < 384) ? W2 : W3;
    bf16_t* T      = (b < 128) ? T0 : (b < 256) ? T1 : (b < 384) ? T2 : T3;
    int c = b & 127;
    for (int k = threadIdx.x; k < KDIM; k += 256)
      T[(size_t)c * KDIM + k] = (bf16_t)W[(size_t)k * FEAT + c];
  } else {
    int i = (b - 512) * 256 + threadIdx.x;
    if (i < NM) { int c = cnt_m[i]; dm[i] = c > 0 ? rsqrtf((float)c) : 0.f; }
    if (i < NA) { int c = cnt_a[i]; da[i] = c > 0 ? rsqrtf((float)c) : 0.f; }
  }
}

// ---------------- projection body: C = sigmoid(A[M,768] @ W + b) -------------
template<bool BF16OUT>
__device__ __forceinline__ void proj_body(
    const float* __restrict__ A, const bf16_t* __restrict__ Wt,
    const float* __restrict__ bias, void* __restrict__ Cout, int M, int rowBase,
    const float* __restrict__ rowscale, float* __restrict__ C2)
{
  __shared__ bf16x8 sm[1024];  // [0..511]=A frags, [512..1023]=B frags
  const int tid = threadIdx.x;
  const int lane = tid & 63;
  const int wid = tid >> 6;

  f32x4 acc[4][4];
  #pragma unroll
  for (int m = 0; m < 4; ++m)
    #pragma unroll
    for (int n = 0; n < 4; ++n)
      acc[m][n] = (f32x4){0.f, 0.f, 0.f, 0.f};

  const int rl0 = ((tid >> 6) << 4) + (tid & 15);
  const int k8 = (tid >> 4) & 3;

  for (int k0 = 0; k0 < KDIM; k0 += 32) {
    #pragma unroll
    for (int i = 0; i < 2; ++i) {
      int rloc = rl0 + 64 * i;
      int rg = rowBase + rloc;
      if (rg > M - 1) rg = M - 1;
      const float* ap = A + (size_t)rg * KDIM + k0 + k8 * 8;
      float4 v0 = *(const float4*)ap;
      float4 v1 = *(const float4*)(ap + 4);
      bf16x8 w;
      w[0] = (bf16_t)v0.x; w[1] = (bf16_t)v0.y; w[2] = (bf16_t)v0.z; w[3] = (bf16_t)v0.w;
      w[4] = (bf16_t)v1.x; w[5] = (bf16_t)v1.y; w[6] = (bf16_t)v1.z; w[7] = (bf16_t)v1.w;
      sm[tid + i * 256] = w;
      sm[512 + tid + i * 256] = *(const bf16x8*)(Wt + (size_t)rloc * KDIM + k0 + k8 * 8);
    }
    __syncthreads();
    bf16x8 a[4], b[4];
    const int fm = (wid >> 1) * 4, fn = (wid & 1) * 4;
    #pragma unroll
    for (int m = 0; m < 4; ++m) a[m] = sm[(fm + m) * 64 + lane];
    #pragma unroll
    for (int n = 0; n < 4; ++n) b[n] = sm[512 + (fn + n) * 64 + lane];
    #pragma unroll
    for (int m = 0; m < 4; ++m)
      #pragma unroll
      for (int n = 0; n < 4; ++n)
        acc[m][n] = __builtin_amdgcn_mfma_f32_16x16x32_bf16(a[m], b[n], acc[m][n], 0, 0, 0);
    __syncthreads();
  }

  // C frag layout: col=lane&15, row=(lane>>4)*4+reg
  const int wRow = (wid >> 1) * 64, wCol = (wid & 1) * 64;
  const int r0 = (lane >> 4) * 4, cc = lane & 15;
  #pragma unroll
  for (int n = 0; n < 4; ++n) {
    int col = wCol + n * 16 + cc;
    float bb = bias[col];
    #pragma unroll
    for (int m = 0; m < 4; ++m) {
      #pragma unroll
      for (int r = 0; r < 4; ++r) {
        int row = rowBase + wRow + m * 16 + r0 + r;
        if (row < M) {
          float v = sigf(acc[m][n][r] + bb);
          float sc = rowscale ? rowscale[row] : 1.0f;
          if constexpr (BF16OUT)
            ((bf16_t*)Cout)[(size_t)row * FEAT + col] = (bf16_t)(v * sc);
          else
            ((float*)Cout)[(size_t)row * FEAT + col] = v * sc;
          if (C2) C2[(size_t)row * FEAT + col] = 0.25f * v;
        }
      }
    }
  }
}

template<bool BF16OUT>
__global__ __launch_bounds__(256) void proj_mfma(
    const float* __restrict__ A, const bf16_t* __restrict__ Wt,
    const float* __restrict__ bias, void* __restrict__ Cout, int M,
    const float* __restrict__ rowscale, float* __restrict__ C2)
{
  proj_body<BF16OUT>(A, Wt, bias, Cout, M, blockIdx.x * 128, rowscale, C2);
}

// fused small projections: vmi (8 blocks), vkey (4), vval (4)
__global__ __launch_bounds__(256) void proj3_kernel(
    const float* __restrict__ x, const float* __restrict__ domain,
    const bf16_t* __restrict__ t0, const bf16_t* __restrict__ t1,
    const bf16_t* __restrict__ t2,
    const float* __restrict__ bsde, const float* __restrict__ bkey,
    const float* __restrict__ bval,
    float* __restrict__ vmi, float* __restrict__ vkey, float* __restrict__ vval)
{
  const int b = blockIdx.x;
  if (b < 8)       proj_body<false>(x, t0, bsde, vmi, BATCH, b * 128, nullptr, nullptr);
  else if (b < 12) proj_body<false>(domain, t1, bkey, vkey, ND, (b - 8) * 128, nullptr, nullptr);
  else             proj_body<false>(domain, t2, bval, vval, ND, (b - 12) * 128, nullptr, nullptr);
}

// ---------------- attention ----------------
__global__ __launch_bounds__(256) void attn_kernel(
    const float* __restrict__ vmi, const float* __restrict__ vkey,
    const float* __restrict__ vval, bf16_t* __restrict__ zm)
{
  const int i = blockIdx.x;
  const int tid = threadIdx.x;
  __shared__ float vs[FEAT];
  __shared__ float al[ND];
  __shared__ float red[4];
  __shared__ float totS;
  if (tid < FEAT) vs[tid] = vmi[(size_t)i * FEAT + tid];
  __syncthreads();
  float part = 0.f;
  for (int j = tid; j < ND; j += 256) {
    const float* kr = vkey + (size_t)j * FEAT;
    float dot = 0.f;
    #pragma unroll 8
    for (int k = 0; k < FEAT; k += 4) {
      float4 kv = *(const float4*)(kr + k);
      dot += vs[k] * kv.x + vs[k + 1] * kv.y + vs[k + 2] * kv.z + vs[k + 3] * kv.w;
    }
    al[j] = dot;
    part += dot;
  }
  #pragma unroll
  for (int o = 32; o > 0; o >>= 1) part += __shfl_down(part, o, 64);
  if ((tid & 63) == 0) red[tid >> 6] = part;
  __syncthreads();
  if (tid == 0) totS = red[0] + red[1] + red[2] + red[3];
  __syncthreads();
  const float inv = 1.0f / totS;
  if (tid < FEAT) {
    float s = 0.f;
    #pragma unroll 4
    for (int j = 0; j < ND; ++j) s += al[j] * vval[(size_t)j * FEAT + tid];
    float z = 0.5f * (s * inv + vs[tid]);
    zm[(size_t)i * FEAT + tid] = (bf16_t)z;
  }
}

// ---------------- row-gather: sum n bf16 rows of ELL list (dword per lane) ----
__device__ __forceinline__ void gatherE(const uint32_t* __restrict__ base,
                                        const u16* __restrict__ row, int n,
                                        float& ax, float& ay)
{
  float lax = 0.f, lay = 0.f;
  int j = 0;
  while (j + 16 <= n) {
    int u[16];
    #pragma unroll
    for (int q = 0; q < 16; ++q) u[q] = row[j + q];
    uint32_t w[16];
    #pragma unroll
    for (int q = 0; q < 16; ++q) w[q] = base[(size_t)u[q] * 64];
    #pragma unroll
    for (int q = 0; q < 16; ++q) {
      lax += __uint_as_float(w[q] << 16);
      lay += __uint_as_float(w[q] & 0xffff0000u);
    }
    j += 16;
  }
  while (j + 4 <= n) {
    int u[4];
    #pragma unroll
    for (int q = 0; q < 4; ++q) u[q] = row[j + q];
    uint32_t w[4];
    #pragma unroll
    for (int q = 0; q < 4; ++q) w[q] = base[(size_t)u[q] * 64];
    #pragma unroll
    for (int q = 0; q < 4; ++q) {
      lax += __uint_as_float(w[q] << 16);
      lay += __uint_as_float(w[q] & 0xffff0000u);
    }
    j += 4;
  }
  while (j < n) {
    int u = row[j];
    uint32_t w = base[(size_t)u * 64];
    lax += __uint_as_float(w << 16);
    lay += __uint_as_float(w & 0xffff0000u);
    ++j;
  }
  ax = lax; ay = lay;
}

// ---- pass1 (api side): y01a = y0a + dinv_a^2 * sum_{m in N(a)} M0y[m] --------
__global__ __launch_bounds__(256) void prop_pass1(
    const bf16_t* __restrict__ M0y, const bf16_t* __restrict__ y0a,
    bf16_t* __restrict__ y01a,
    const u16* __restrict__ adja, const int* __restrict__ cnt_a,
    const float* __restrict__ da)
{
  const int a = blockIdx.x * 4 + (threadIdx.x >> 6);
  const int lane = threadIdx.x & 63;
  int n = cnt_a[a]; if (n > MD) n = MD;
  float ax, ay;
  gatherE((const uint32_t*)M0y + lane, adja + (size_t)a * MD, n, ax, ay);
  const float d = da[a];
  const float s2 = d * d;
  uint32_t y0 = ((const uint32_t*)y0a)[(size_t)a * 64 + lane];
  bf16x2 pk;
  pk[0] = (bf16_t)(__uint_as_float(y0 << 16) + s2 * ax);
  pk[1] = (bf16_t)(__uint_as_float(y0 & 0xffff0000u) + s2 * ay);
  *(bf16x2*)(y01a + (size_t)a * FEAT + 2 * lane) = pk;
}

// ---- pass2 (mashup side): Sy = M0y + dinv_m^2 * sum_{a in N(m)} y01a[a] ------
__global__ __launch_bounds__(256) void prop_pass2(
    const bf16_t* __restrict__ y01a, const bf16_t* __restrict__ M0y,
    bf16_t* __restrict__ Sy,
    const u16* __restrict__ adjm, const int* __restrict__ cnt_m,
    const float* __restrict__ dm)
{
  const int m = blockIdx.x * 4 + (threadIdx.x >> 6);
  const int lane = threadIdx.x & 63;
  int n = cnt_m[m]; if (n > MD) n = MD;
  float ax, ay;
  gatherE((const uint32_t*)y01a + lane, adjm + (size_t)m * MD, n, ax, ay);
  const float d = dm[m];
  const float s2 = d * d;
  uint32_t m0 = ((const uint32_t*)M0y)[(size_t)m * 64 + lane];
  bf16x2 pk;
  pk[0] = (bf16_t)(__uint_as_float(m0 << 16) + s2 * ax);
  pk[1] = (bf16_t)(__uint_as_float(m0 & 0xffff0000u) + s2 * ay);
  *(bf16x2*)(Sy + (size_t)m * FEAT + 2 * lane) = pk;
}

// ---- pass3 (api side): O = 0.25*A0 + 0.25*dinv_a * sum_{m in N(a)} Sy[m] -----
__global__ __launch_bounds__(256) void prop_pass3(
    const bf16_t* __restrict__ Sy, const float* __restrict__ outA,
    bf16_t* __restrict__ Obf,
    const u16* __restrict__ adja, const int* __restrict__ cnt_a,
    const float* __restrict__ da)
{
  const int a = blockIdx.x * 4 + (threadIdx.x >> 6);
  const int lane = threadIdx.x & 63;
  int n = cnt_a[a]; if (n > MD) n = MD;
  float ax, ay;
  gatherE((const uint32_t*)Sy + lane, adja + (size_t)a * MD, n, ax, ay);
  const float q = 0.25f * da[a];
  const float2 prev = *(const float2*)(outA + (size_t)a * FEAT + 2 * lane);
  bf16x2 pk;
  pk[0] = (bf16_t)(prev.x + q * ax);
  pk[1] = (bf16_t)(prev.y + q * ay);
  *(bf16x2*)(Obf + (size_t)a * FEAT + 2 * lane) = pk;
}

// ---------------- pred = Z[1024,128] @ O[50000,128]^T, bf16 MFMA --------------
__global__ __launch_bounds__(256) void pred_mfma(
    const bf16_t* __restrict__ Z, const bf16_t* __restrict__ O,
    float* __restrict__ out)
{
  const int lane = threadIdx.x & 63;
  const int wid = threadIdx.x >> 6;
  const int nBase = blockIdx.x * 256 + wid * 64;
  const int cc = lane & 15;
  const int kOff = (lane >> 4) * 8;

  bf16x8 b[4][4];
  #pragma unroll
  for (int n = 0; n < 4; ++n) {
    int c = nBase + n * 16 + cc;
    if (c > NA - 1) c = NA - 1;
    #pragma unroll
    for (int kk = 0; kk < 4; ++kk)
      b[n][kk] = *(const bf16x8*)(O + (size_t)c * FEAT + kk * 32 + kOff);
  }

  const int r0 = (lane >> 4) * 4;
  #pragma unroll
  for (int it = 0; it < 4; ++it) {
    const int iBase = blockIdx.y * 256 + it * 64;
    f32x4 acc[4][4];
    #pragma unroll
    for (int m = 0; m < 4; ++m)
      #pragma unroll
      for (int n = 0; n < 4; ++n)
        acc[m][n] = (f32x4){0.f, 0.f, 0.f, 0.f};

    #pragma unroll
    for (int kk = 0; kk < 4; ++kk) {
      bf16x8 a[4];
      #pragma unroll
      for (int m = 0; m < 4; ++m)
        a[m] = *(const bf16x8*)(Z + (size_t)(iBase + cc + m * 16) * FEAT + kk * 32 + kOff);
      #pragma unroll
      for (int m = 0; m < 4; ++m)
        #pragma unroll
        for (int n = 0; n < 4; ++n)
          acc[m][n] = __builtin_amdgcn_mfma_f32_16x16x32_bf16(a[m], b[n][kk], acc[m][n], 0, 0, 0);
    }

    #pragma unroll
    for (int n = 0; n < 4; ++n) {
      int col = nBase + n * 16 + cc;
      if (col < NA) {
        #pragma unroll
        for (int m = 0; m < 4; ++m) {
          #pragma unroll
          for (int r = 0; r < 4; ++r) {
            int row = iBase + m * 16 + r0 + r;
            __builtin_nontemporal_store(acc[m][n][r], &out[(size_t)row * NA + col]);
          }
        }
      }
    }
  }
}

static inline char* alignup(char* p, size_t a) {
  return (char*)(((uintptr_t)p + a - 1) & ~(uintptr_t)(a - 1));
}

extern "C" void kernel_launch(void* const* d_in, const int* in_sizes, int n_in,
                              void* d_out, int out_size, void* d_ws, size_t ws_size,
                              hipStream_t stream) {
  const float* x      = (const float*)d_in[0];
  const float* mashup = (const float*)d_in[1];
  const float* domain = (const float*)d_in[2];
  const float* api    = (const float*)d_in[3];
  const float* Wsde   = (const float*)d_in[4];
  const float* bsde   = (const float*)d_in[5];
  const float* Wval   = (const float*)d_in[6];
  const float* bval   = (const float*)d_in[7];
  const float* Wkey   = (const float*)d_in[8];
  const float* bkey   = (const float*)d_in[9];
  const float* Wsie   = (const float*)d_in[10];
  const float* bsie   = (const float*)d_in[11];
  const int* esrc     = (const int*)d_in[12];
  const int* edst     = (const int*)d_in[13];
  float* out = (float*)d_out;

  // workspace layout (~118 MB)
  char* p = (char*)d_ws;
  bf16_t* M0y  = (bf16_t*)p; p += (size_t)NM * FEAT * 2;          // 12.8MB
  bf16_t* y0a  = (bf16_t*)p; p += (size_t)NA * FEAT * 2;          // 12.8MB
  bf16_t* y01a = (bf16_t*)p; p += (size_t)NA * FEAT * 2;          // 12.8MB
  bf16_t* Sy   = (bf16_t*)p; p += (size_t)NM * FEAT * 2;          // 12.8MB
  float*  outA = (float*)p;  p += (size_t)NA * FEAT * 4;          // 25.6MB
  bf16_t* Obf  = (bf16_t*)p; p += (size_t)NA * FEAT * 2;          // 12.8MB
  u16*    adjm = (u16*)p;    p += (size_t)NM * MD * 2;            // 12.8MB
  u16*    adja = (u16*)p;    p += (size_t)NA * MD * 2;            // 12.8MB
  float*  vmi  = (float*)p;  p += (size_t)BATCH * FEAT * 4;
  float*  vkey = (float*)p;  p += (size_t)ND * FEAT * 4;
  float*  vval = (float*)p;  p += (size_t)ND * FEAT * 4;
  bf16_t* zm   = (bf16_t*)p; p += (size_t)BATCH * FEAT * 2;
  int* cnt_m = (int*)p; p += (size_t)NM * 4;
  int* cnt_a = (int*)p; p += (size_t)NA * 4;
  float* dm  = (float*)p; p += (size_t)NM * 4;
  float* da  = (float*)p; p += (size_t)NA * 4;
  int* bcur  = (int*)p; p += 512 * 4;
  p = alignup(p, 16);
  bf16_t* wt0 = (bf16_t*)p; p += (size_t)FEAT * KDIM * 2;
  bf16_t* wt1 = (bf16_t*)p; p += (size_t)FEAT * KDIM * 2;
  bf16_t* wt2 = (bf16_t*)p; p += (size_t)FEAT * KDIM * 2;
  bf16_t* wt3 = (bf16_t*)p; p += (size_t)FEAT * KDIM * 2;
  // rec (2*NBIN*CAP*4B = 16.1MB) overlays M0y+y0a (25.6MB): dead before
  // proj_mfma writes M0y/y0a (fill_ell2 completes first, same stream).
  uint32_t* rec = (uint32_t*)M0y;

  hipMemsetAsync(bcur, 0, 512 * sizeof(int), stream);

  // ---- graph build: two-level binning (157K global atomics vs 3.2M) ----
  fill_bin<<<F1B, 256, 0, stream>>>(esrc, edst, bcur, rec);
  fill_ell2<<<2 * NBIN, 256, 0, stream>>>(rec, bcur, adjm, adja, cnt_m, cnt_a);
  util_kernel<<<512 + (NM + 255) / 256, 256, 0, stream>>>(
      Wsde, Wkey, Wval, Wsie, wt0, wt1, wt2, wt3, cnt_m, cnt_a, dm, da);

  // ---- projections ----
  proj3_kernel<<<16, 256, 0, stream>>>(x, domain, wt0, wt1, wt2,
                                       bsde, bkey, bval, vmi, vkey, vval);
  attn_kernel<<<BATCH, 256, 0, stream>>>(vmi, vkey, vval, zm);

  // mashup: M0y = dm[m]*sigmoid(...); api: y0a = da[a]*sigmoid(...), outA = 0.25*sig
  proj_mfma<true><<<(NM + 127) / 128, 256, 0, stream>>>(mashup, wt0, bsde, M0y, NM,
                                                        dm, nullptr);
  proj_mfma<true><<<(NA + 127) / 128, 256, 0, stream>>>(api, wt3, bsie, y0a, NA,
                                                        da, outA);

  // ---- bipartite LightGCN: out_api = 0.25*(A0 + P^T(M0+M1+M2)) ----
  prop_pass1<<<NA / 4, 256, 0, stream>>>(M0y, y0a, y01a, adja, cnt_a, da);
  prop_pass2<<<NM / 4, 256, 0, stream>>>(y01a, M0y, Sy, adjm, cnt_m, dm);
  prop_pass3<<<NA / 4, 256, 0, stream>>>(Sy, outA, Obf, adja, cnt_a, da);

  pred_mfma<<<dim3((NA + 255) / 256, BATCH / 256), 256, 0, stream>>>(zm, Obf, out);
}

// Round 10
// 492.203 us; speedup vs baseline: 1.2835x; 1.1161x over previous
//
#include <hip/hip_runtime.h>
#include <hip/hip_bf16.h>
#include <cstddef>
#include <cstdint>

#define NM 50000
#define NA 50000
#define ND 500
#define FEAT 128
#define KDIM 768
#define BATCH 1024
#define NEDGE 1600000
#define MD 128            // ELL row capacity (deg ~ Poisson(32); P(>128) ~ 1e-38)

#define NBIN 196          // ceil(50000/256) node bins of 256 nodes
#define CAP 10240         // records per bin (expected 8163, 23 sigma headroom)
#define F1B 400           // fill_bin blocks
#define F1E (NEDGE / F1B) // 4000 edges per block (exact)

typedef __bf16 bf16_t;
typedef bf16_t bf16x8 __attribute__((ext_vector_type(8)));
typedef bf16_t bf16x4 __attribute__((ext_vector_type(4)));
typedef float f32x4 __attribute__((ext_vector_type(4)));
typedef float f32x2 __attribute__((ext_vector_type(2)));
typedef unsigned short u16;
typedef unsigned char u8;

__device__ __forceinline__ float sigf(float x) { return 1.0f / (1.0f + __expf(-x)); }

// ---- fp8 e4m3 (OCP) helpers: HW v_cvt pack/unpack ----
__device__ __forceinline__ float4 dec4fp8(uint32_t w) {
  f32x2 lo = __builtin_amdgcn_cvt_pk_f32_fp8(w, false);
  f32x2 hi = __builtin_amdgcn_cvt_pk_f32_fp8(w, true);
  return make_float4(lo[0], lo[1], hi[0], hi[1]);
}
__device__ __forceinline__ u8 enc1fp8(float a) {
  return (u8)(__builtin_amdgcn_cvt_pk_fp8_f32(a, a, 0, false) & 0xff);
}

// ---------------- fill pass 1: edges -> bin-bucketed packed records -----------
// Edges staged in LDS (single global read). LDS histogram per 256-node bin,
// ONE global atomic per (block,bin) reservation, then packed-record emission
// into contiguous runs. Node ids < 65536 -> (node<<16|neighbor) in 32 bits.
__global__ __launch_bounds__(256) void fill_bin(
    const int* __restrict__ src, const int* __restrict__ dst,
    int* __restrict__ bcur, uint32_t* __restrict__ rec /* [2*NBIN][CAP] */)
{
  __shared__ uint32_t edg[F1E];      // 16 KB
  __shared__ int hist[2 * NBIN];
  __shared__ int base[2 * NBIN];
  const int tid = threadIdx.x;
  for (int i = tid; i < 2 * NBIN; i += 256) hist[i] = 0;
  __syncthreads();
  const int e0 = blockIdx.x * F1E;
  for (int i = tid; i < F1E; i += 256) {
    int s = __builtin_nontemporal_load(&src[e0 + i]);
    int d = __builtin_nontemporal_load(&dst[e0 + i]);
    edg[i] = ((uint32_t)s << 16) | (uint32_t)d;
    atomicAdd(&hist[s >> 8], 1);
    atomicAdd(&hist[NBIN + (d >> 8)], 1);
  }
  __syncthreads();
  for (int i = tid; i < 2 * NBIN; i += 256) {
    int c = hist[i];
    base[i] = c ? atomicAdd(&bcur[i], c) : 0;
    hist[i] = 0;  // reuse as emit cursor
  }
  __syncthreads();
  for (int i = tid; i < F1E; i += 256) {
    uint32_t e = edg[i];
    int s = (int)(e >> 16), d = (int)(e & 0xffffu);
    int bm = s >> 8, ba = NBIN + (d >> 8);
    int rm = base[bm] + atomicAdd(&hist[bm], 1);
    int ra = base[ba] + atomicAdd(&hist[ba], 1);
    if (rm < CAP) rec[(size_t)bm * CAP + rm] = e;
    if (ra < CAP) rec[(size_t)ba * CAP + ra] = ((uint32_t)d << 16) | (uint32_t)s;
  }
}

// ---------------- fill pass 2: records -> ELL rows + exact degrees ------------
__global__ __launch_bounds__(256) void fill_ell2(
    const uint32_t* __restrict__ rec, const int* __restrict__ bcur,
    u16* __restrict__ adjm, u16* __restrict__ adja,
    int* __restrict__ cnt_m, int* __restrict__ cnt_a)
{
  __shared__ int cnt256[256];
  const int g = blockIdx.x;                 // 0..2*NBIN-1
  const int side = g >= NBIN;
  const int bin = side ? g - NBIN : g;
  u16* adj = side ? adja : adjm;
  int* cnt = side ? cnt_a : cnt_m;
  cnt256[threadIdx.x] = 0;
  __syncthreads();
  int n = bcur[g]; if (n > CAP) n = CAP;
  const uint32_t* rb = rec + (size_t)g * CAP;
  for (int i = threadIdx.x; i < n; i += 256) {
    uint32_t r = rb[i];
    int node = (int)(r >> 16);
    int rk = atomicAdd(&cnt256[node & 255], 1);
    if (rk < MD) adj[(size_t)node * MD + rk] = (u16)(r & 0xffffu);
  }
  __syncthreads();
  int node = bin * 256 + threadIdx.x;
  if (node < NM) cnt[node] = cnt256[threadIdx.x];
}

// ---------------- util: 4x weight transpose->bf16 + deg->dinv ----------------
__global__ __launch_bounds__(256) void util_kernel(
    const float* __restrict__ W0, const float* __restrict__ W1,
    const float* __restrict__ W2, const float* __restrict__ W3,
    bf16_t* __restrict__ T0, bf16_t* __restrict__ T1,
    bf16_t* __restrict__ T2, bf16_t* __restrict__ T3,
    const int* __restrict__ cnt_m, const int* __restrict__ cnt_a,
    float* __restrict__ dm, float* __restrict__ da)
{
  const int b = blockIdx.x;
  if (b < 512) {
    const float* W = (b < 128) ? W0 : (b < 256) ? W1 : (b < 384) ? W2 : W3;
    bf16_t* T      = (b < 128) ? T0 : (b < 256) ? T1 : (b < 384) ? T2 : T3;
    int c = b & 127;
    for (int k = threadIdx.x; k < KDIM; k += 256)
      T[(size_t)c * KDIM + k] = (bf16_t)W[(size_t)k * FEAT + c];
  } else {
    int i = (b - 512) * 256 + threadIdx.x;
    if (i < NM) { int c = cnt_m[i]; dm[i] = c > 0 ? rsqrtf((float)c) : 0.f; }
    if (i < NA) { int c = cnt_a[i]; da[i] = c > 0 ? rsqrtf((float)c) : 0.f; }
  }
}

// ---------------- projection body: C = sigmoid(A[M,768] @ W + b) -------------
// OM: 0 = fp32 out, 2 = fp8(e4m3) out (row-scaled). C2: optional 0.25*sig bf16.
template<int OM>
__device__ __forceinline__ void proj_body(
    const float* __restrict__ A, const bf16_t* __restrict__ Wt,
    const float* __restrict__ bias, void* __restrict__ Cout, int M, int rowBase,
    const float* __restrict__ rowscale, bf16_t* __restrict__ C2)
{
  __shared__ bf16x8 sm[1024];  // [0..511]=A frags, [512..1023]=B frags
  const int tid = threadIdx.x;
  const int lane = tid & 63;
  const int wid = tid >> 6;

  f32x4 acc[4][4];
  #pragma unroll
  for (int m = 0; m < 4; ++m)
    #pragma unroll
    for (int n = 0; n < 4; ++n)
      acc[m][n] = (f32x4){0.f, 0.f, 0.f, 0.f};

  const int rl0 = ((tid >> 6) << 4) + (tid & 15);
  const int k8 = (tid >> 4) & 3;

  for (int k0 = 0; k0 < KDIM; k0 += 32) {
    #pragma unroll
    for (int i = 0; i < 2; ++i) {
      int rloc = rl0 + 64 * i;
      int rg = rowBase + rloc;
      if (rg > M - 1) rg = M - 1;
      const float* ap = A + (size_t)rg * KDIM + k0 + k8 * 8;
      float4 v0 = *(const float4*)ap;
      float4 v1 = *(const float4*)(ap + 4);
      bf16x8 w;
      w[0] = (bf16_t)v0.x; w[1] = (bf16_t)v0.y; w[2] = (bf16_t)v0.z; w[3] = (bf16_t)v0.w;
      w[4] = (bf16_t)v1.x; w[5] = (bf16_t)v1.y; w[6] = (bf16_t)v1.z; w[7] = (bf16_t)v1.w;
      sm[tid + i * 256] = w;
      sm[512 + tid + i * 256] = *(const bf16x8*)(Wt + (size_t)rloc * KDIM + k0 + k8 * 8);
    }
    __syncthreads();
    bf16x8 a[4], b[4];
    const int fm = (wid >> 1) * 4, fn = (wid & 1) * 4;
    #pragma unroll
    for (int m = 0; m < 4; ++m) a[m] = sm[(fm + m) * 64 + lane];
    #pragma unroll
    for (int n = 0; n < 4; ++n) b[n] = sm[512 + (fn + n) * 64 + lane];
    #pragma unroll
    for (int m = 0; m < 4; ++m)
      #pragma unroll
      for (int n = 0; n < 4; ++n)
        acc[m][n] = __builtin_amdgcn_mfma_f32_16x16x32_bf16(a[m], b[n], acc[m][n], 0, 0, 0);
    __syncthreads();
  }

  // C frag layout: col=lane&15, row=(lane>>4)*4+reg
  const int wRow = (wid >> 1) * 64, wCol = (wid & 1) * 64;
  const int r0 = (lane >> 4) * 4, cc = lane & 15;
  #pragma unroll
  for (int n = 0; n < 4; ++n) {
    int col = wCol + n * 16 + cc;
    float bb = bias[col];
    #pragma unroll
    for (int m = 0; m < 4; ++m) {
      #pragma unroll
      for (int r = 0; r < 4; ++r) {
        int row = rowBase + wRow + m * 16 + r0 + r;
        if (row < M) {
          float v = sigf(acc[m][n][r] + bb);
          float sc = rowscale ? rowscale[row] : 1.0f;
          if constexpr (OM == 2)
            ((u8*)Cout)[(size_t)row * FEAT + col] = enc1fp8(v * sc);
          else
            ((float*)Cout)[(size_t)row * FEAT + col] = v * sc;
          if (C2) C2[(size_t)row * FEAT + col] = (bf16_t)(0.25f * v);
        }
      }
    }
  }
}

template<int OM>
__global__ __launch_bounds__(256) void proj_mfma(
    const float* __restrict__ A, const bf16_t* __restrict__ Wt,
    const float* __restrict__ bias, void* __restrict__ Cout, int M,
    const float* __restrict__ rowscale, bf16_t* __restrict__ C2)
{
  proj_body<OM>(A, Wt, bias, Cout, M, blockIdx.x * 128, rowscale, C2);
}

// fused small projections: vmi (8 blocks), vkey (4), vval (4)
__global__ __launch_bounds__(256) void proj3_kernel(
    const float* __restrict__ x, const float* __restrict__ domain,
    const bf16_t* __restrict__ t0, const bf16_t* __restrict__ t1,
    const bf16_t* __restrict__ t2,
    const float* __restrict__ bsde, const float* __restrict__ bkey,
    const float* __restrict__ bval,
    float* __restrict__ vmi, float* __restrict__ vkey, float* __restrict__ vval)
{
  const int b = blockIdx.x;
  if (b < 8)       proj_body<0>(x, t0, bsde, vmi, BATCH, b * 128, nullptr, nullptr);
  else if (b < 12) proj_body<0>(domain, t1, bkey, vkey, ND, (b - 8) * 128, nullptr, nullptr);
  else             proj_body<0>(domain, t2, bval, vval, ND, (b - 12) * 128, nullptr, nullptr);
}

// ---------------- attention ----------------
__global__ __launch_bounds__(256) void attn_kernel(
    const float* __restrict__ vmi, const float* __restrict__ vkey,
    const float* __restrict__ vval, bf16_t* __restrict__ zm)
{
  const int i = blockIdx.x;
  const int tid = threadIdx.x;
  __shared__ float vs[FEAT];
  __shared__ float al[ND];
  __shared__ float red[4];
  __shared__ float totS;
  if (tid < FEAT) vs[tid] = vmi[(size_t)i * FEAT + tid];
  __syncthreads();
  float part = 0.f;
  for (int j = tid; j < ND; j += 256) {
    const float* kr = vkey + (size_t)j * FEAT;
    float dot = 0.f;
    #pragma unroll 8
    for (int k = 0; k < FEAT; k += 4) {
      float4 kv = *(const float4*)(kr + k);
      dot += vs[k] * kv.x + vs[k + 1] * kv.y + vs[k + 2] * kv.z + vs[k + 3] * kv.w;
    }
    al[j] = dot;
    part += dot;
  }
  #pragma unroll
  for (int o = 32; o > 0; o >>= 1) part += __shfl_down(part, o, 64);
  if ((tid & 63) == 0) red[tid >> 6] = part;
  __syncthreads();
  if (tid == 0) totS = red[0] + red[1] + red[2] + red[3];
  __syncthreads();
  const float inv = 1.0f / totS;
  if (tid < FEAT) {
    float s = 0.f;
    #pragma unroll 4
    for (int j = 0; j < ND; ++j) s += al[j] * vval[(size_t)j * FEAT + tid];
    float z = 0.5f * (s * inv + vs[tid]);
    zm[(size_t)i * FEAT + tid] = (bf16_t)z;
  }
}

// ---------------- fp8 row-gather: half-wave per alternate neighbor ------------
// Row = 128 fp8 = 32 dwords. Lanes 0-31 gather even-indexed neighbors, lanes
// 32-63 odd; caller combines with shfl_xor(32). base32 pre-offset by sl.
__device__ __forceinline__ float4 gatherF8(const uint32_t* __restrict__ base32,
                                           const u16* __restrict__ row,
                                           int n, int half)
{
  float4 acc = make_float4(0.f, 0.f, 0.f, 0.f);
  int j = half;
  while (j + 14 < n) {
    int u[8];
    #pragma unroll
    for (int q = 0; q < 8; ++q) u[q] = row[j + 2 * q];
    uint32_t w[8];
    #pragma unroll
    for (int q = 0; q < 8; ++q) w[q] = base32[(size_t)u[q] * 32];
    #pragma unroll
    for (int q = 0; q < 8; ++q) {
      float4 v = dec4fp8(w[q]);
      acc.x += v.x; acc.y += v.y; acc.z += v.z; acc.w += v.w;
    }
    j += 16;
  }
  while (j < n) {
    float4 v = dec4fp8(base32[(size_t)row[j] * 32]);
    acc.x += v.x; acc.y += v.y; acc.z += v.z; acc.w += v.w;
    j += 2;
  }
  return acc;
}

#define REDUCE_HALVES(acc)                    \
  acc.x += __shfl_xor(acc.x, 32);             \
  acc.y += __shfl_xor(acc.y, 32);             \
  acc.z += __shfl_xor(acc.z, 32);             \
  acc.w += __shfl_xor(acc.w, 32);

// ---- pass1 (api side): y01a = y0a + da^2 * sum_{m in N(a)} M0y[m] ------------
__global__ __launch_bounds__(256) void prop_p1(
    const uint32_t* __restrict__ M0y8, const uint32_t* __restrict__ y0a8,
    uint32_t* __restrict__ y01a8,
    const u16* __restrict__ adja, const int* __restrict__ cnt_a,
    const float* __restrict__ da)
{
  const int a = blockIdx.x * 4 + (threadIdx.x >> 6);
  const int lane = threadIdx.x & 63;
  const int half = lane >> 5, sl = lane & 31;
  int n = cnt_a[a]; if (n > MD) n = MD;
  float4 acc = gatherF8(M0y8 + sl, adja + (size_t)a * MD, n, half);
  REDUCE_HALVES(acc)
  if (half == 0) {
    const float d = da[a];
    const float s2 = d * d;
    float4 b = dec4fp8(y0a8[(size_t)a * 32 + sl]);
    uint32_t o = __builtin_amdgcn_cvt_pk_fp8_f32(b.x + s2 * acc.x, b.y + s2 * acc.y, 0, false);
    o = __builtin_amdgcn_cvt_pk_fp8_f32(b.z + s2 * acc.z, b.w + s2 * acc.w, o, true);
    y01a8[(size_t)a * 32 + sl] = o;
  }
}

// ---- pass2 (mashup side): Sy = M0y + dm^2 * sum_{a in N(m)} y01a[a] ----------
__global__ __launch_bounds__(256) void prop_p2(
    const uint32_t* __restrict__ y01a8, const uint32_t* __restrict__ M0y8,
    uint32_t* __restrict__ Sy8,
    const u16* __restrict__ adjm, const int* __restrict__ cnt_m,
    const float* __restrict__ dm)
{
  const int m = blockIdx.x * 4 + (threadIdx.x >> 6);
  const int lane = threadIdx.x & 63;
  const int half = lane >> 5, sl = lane & 31;
  int n = cnt_m[m]; if (n > MD) n = MD;
  float4 acc = gatherF8(y01a8 + sl, adjm + (size_t)m * MD, n, half);
  REDUCE_HALVES(acc)
  if (half == 0) {
    const float d = dm[m];
    const float s2 = d * d;
    float4 b = dec4fp8(M0y8[(size_t)m * 32 + sl]);
    uint32_t o = __builtin_amdgcn_cvt_pk_fp8_f32(b.x + s2 * acc.x, b.y + s2 * acc.y, 0, false);
    o = __builtin_amdgcn_cvt_pk_fp8_f32(b.z + s2 * acc.z, b.w + s2 * acc.w, o, true);
    Sy8[(size_t)m * 32 + sl] = o;
  }
}

// ---- pass3 (api side): O = 0.25*A0 + 0.25*da * sum_{m in N(a)} Sy[m] ---------
__global__ __launch_bounds__(256) void prop_p3(
    const uint32_t* __restrict__ Sy8, const bf16_t* __restrict__ outA,
    bf16_t* __restrict__ Obf,
    const u16* __restrict__ adja, const int* __restrict__ cnt_a,
    const float* __restrict__ da)
{
  const int a = blockIdx.x * 4 + (threadIdx.x >> 6);
  const int lane = threadIdx.x & 63;
  const int half = lane >> 5, sl = lane & 31;
  int n = cnt_a[a]; if (n > MD) n = MD;
  float4 acc = gatherF8(Sy8 + sl, adja + (size_t)a * MD, n, half);
  REDUCE_HALVES(acc)
  if (half == 0) {
    const float q = 0.25f * da[a];
    bf16x4 pv = *(const bf16x4*)(outA + (size_t)a * FEAT + 4 * sl);
    bf16x4 o;
    o[0] = (bf16_t)((float)pv[0] + q * acc.x);
    o[1] = (bf16_t)((float)pv[1] + q * acc.y);
    o[2] = (bf16_t)((float)pv[2] + q * acc.z);
    o[3] = (bf16_t)((float)pv[3] + q * acc.w);
    *(bf16x4*)(Obf + (size_t)a * FEAT + 4 * sl) = o;
  }
}

// ---------------- pred = Z[1024,128] @ O[50000,128]^T, bf16 MFMA --------------
__global__ __launch_bounds__(256) void pred_mfma(
    const bf16_t* __restrict__ Z, const bf16_t* __restrict__ O,
    float* __restrict__ out)
{
  const int lane = threadIdx.x & 63;
  const int wid = threadIdx.x >> 6;
  const int nBase = blockIdx.x * 256 + wid * 64;
  const int cc = lane & 15;
  const int kOff = (lane >> 4) * 8;

  bf16x8 b[4][4];
  #pragma unroll
  for (int n = 0; n < 4; ++n) {
    int c = nBase + n * 16 + cc;
    if (c > NA - 1) c = NA - 1;
    #pragma unroll
    for (int kk = 0; kk < 4; ++kk)
      b[n][kk] = *(const bf16x8*)(O + (size_t)c * FEAT + kk * 32 + kOff);
  }

  const int r0 = (lane >> 4) * 4;
  #pragma unroll
  for (int it = 0; it < 4; ++it) {
    const int iBase = blockIdx.y * 256 + it * 64;
    f32x4 acc[4][4];
    #pragma unroll
    for (int m = 0; m < 4; ++m)
      #pragma unroll
      for (int n = 0; n < 4; ++n)
        acc[m][n] = (f32x4){0.f, 0.f, 0.f, 0.f};

    #pragma unroll
    for (int kk = 0; kk < 4; ++kk) {
      bf16x8 a[4];
      #pragma unroll
      for (int m = 0; m < 4; ++m)
        a[m] = *(const bf16x8*)(Z + (size_t)(iBase + cc + m * 16) * FEAT + kk * 32 + kOff);
      #pragma unroll
      for (int m = 0; m < 4; ++m)
        #pragma unroll
        for (int n = 0; n < 4; ++n)
          acc[m][n] = __builtin_amdgcn_mfma_f32_16x16x32_bf16(a[m], b[n][kk], acc[m][n], 0, 0, 0);
    }

    #pragma unroll
    for (int n = 0; n < 4; ++n) {
      int col = nBase + n * 16 + cc;
      if (col < NA) {
        #pragma unroll
        for (int m = 0; m < 4; ++m) {
          #pragma unroll
          for (int r = 0; r < 4; ++r) {
            int row = iBase + m * 16 + r0 + r;
            __builtin_nontemporal_store(acc[m][n][r], &out[(size_t)row * NA + col]);
          }
        }
      }
    }
  }
}

static inline char* alignup(char* p, size_t a) {
  return (char*)(((uintptr_t)p + a - 1) & ~(uintptr_t)(a - 1));
}

extern "C" void kernel_launch(void* const* d_in, const int* in_sizes, int n_in,
                              void* d_out, int out_size, void* d_ws, size_t ws_size,
                              hipStream_t stream) {
  const float* x      = (const float*)d_in[0];
  const float* mashup = (const float*)d_in[1];
  const float* domain = (const float*)d_in[2];
  const float* api    = (const float*)d_in[3];
  const float* Wsde   = (const float*)d_in[4];
  const float* bsde   = (const float*)d_in[5];
  const float* Wval   = (const float*)d_in[6];
  const float* bval   = (const float*)d_in[7];
  const float* Wkey   = (const float*)d_in[8];
  const float* bkey   = (const float*)d_in[9];
  const float* Wsie   = (const float*)d_in[10];
  const float* bsie   = (const float*)d_in[11];
  const int* esrc     = (const int*)d_in[12];
  const int* edst     = (const int*)d_in[13];
  float* out = (float*)d_out;

  // workspace layout (~90 MB)
  char* p = (char*)d_ws;
  u8*     M0y8  = (u8*)p; p += (size_t)NM * FEAT;                 // 6.4MB
  u8*     y0a8  = (u8*)p; p += (size_t)NA * FEAT;                 // 6.4MB
  u8*     y01a8 = (u8*)p; p += (size_t)NA * FEAT;                 // 6.4MB
  u8*     Sy8   = (u8*)p; p += (size_t)NM * FEAT;                 // 6.4MB
  bf16_t* outA  = (bf16_t*)p; p += (size_t)NA * FEAT * 2;         // 12.8MB
  bf16_t* Obf   = (bf16_t*)p; p += (size_t)NA * FEAT * 2;         // 12.8MB
  u16*    adjm  = (u16*)p;    p += (size_t)NM * MD * 2;           // 12.8MB
  u16*    adja  = (u16*)p;    p += (size_t)NA * MD * 2;           // 12.8MB
  float*  vmi   = (float*)p;  p += (size_t)BATCH * FEAT * 4;
  float*  vkey  = (float*)p;  p += (size_t)ND * FEAT * 4;
  float*  vval  = (float*)p;  p += (size_t)ND * FEAT * 4;
  bf16_t* zm    = (bf16_t*)p; p += (size_t)BATCH * FEAT * 2;
  int* cnt_m = (int*)p; p += (size_t)NM * 4;
  int* cnt_a = (int*)p; p += (size_t)NA * 4;
  float* dm  = (float*)p; p += (size_t)NM * 4;
  float* da  = (float*)p; p += (size_t)NA * 4;
  int* bcur  = (int*)p; p += 512 * 4;
  p = alignup(p, 16);
  bf16_t* wt0 = (bf16_t*)p; p += (size_t)FEAT * KDIM * 2;
  bf16_t* wt1 = (bf16_t*)p; p += (size_t)FEAT * KDIM * 2;
  bf16_t* wt2 = (bf16_t*)p; p += (size_t)FEAT * KDIM * 2;
  bf16_t* wt3 = (bf16_t*)p; p += (size_t)FEAT * KDIM * 2;
  // rec (2*NBIN*CAP*4B = 16.1MB) overlays M0y8+y0a8+y01a8 (19.2MB): dead
  // before proj_mfma/prop write those (fill_ell2 completes first, same stream).
  uint32_t* rec = (uint32_t*)M0y8;

  hipMemsetAsync(bcur, 0, 512 * sizeof(int), stream);

  // ---- graph build: two-level binning (157K global atomics vs 3.2M) ----
  fill_bin<<<F1B, 256, 0, stream>>>(esrc, edst, bcur, rec);
  fill_ell2<<<2 * NBIN, 256, 0, stream>>>(rec, bcur, adjm, adja, cnt_m, cnt_a);
  util_kernel<<<512 + (NM + 255) / 256, 256, 0, stream>>>(
      Wsde, Wkey, Wval, Wsie, wt0, wt1, wt2, wt3, cnt_m, cnt_a, dm, da);

  // ---- projections ----
  proj3_kernel<<<16, 256, 0, stream>>>(x, domain, wt0, wt1, wt2,
                                       bsde, bkey, bval, vmi, vkey, vval);
  attn_kernel<<<BATCH, 256, 0, stream>>>(vmi, vkey, vval, zm);

  // mashup: M0y8 = fp8(dm[m]*sig); api: y0a8 = fp8(da[a]*sig), outA = bf16(0.25*sig)
  proj_mfma<2><<<(NM + 127) / 128, 256, 0, stream>>>(mashup, wt0, bsde, M0y8, NM,
                                                     dm, nullptr);
  proj_mfma<2><<<(NA + 127) / 128, 256, 0, stream>>>(api, wt3, bsie, y0a8, NA,
                                                     da, outA);

  // ---- bipartite LightGCN (fp8 gathers): out_api = 0.25*(A0 + P^T(M0+M1+M2)) ----
  prop_p1<<<NA / 4, 256, 0, stream>>>((const uint32_t*)M0y8, (const uint32_t*)y0a8,
                                      (uint32_t*)y01a8, adja, cnt_a, da);
  prop_p2<<<NM / 4, 256, 0, stream>>>((const uint32_t*)y01a8, (const uint32_t*)M0y8,
                                      (uint32_t*)Sy8, adjm, cnt_m, dm);
  prop_p3<<<NA / 4, 256, 0, stream>>>((const uint32_t*)Sy8, outA, Obf,
                                      adja, cnt_a, da);

  pred_mfma<<<dim3((NA + 255) / 256, BATCH / 256), 256, 0, stream>>>(zm, Obf, out);
}

// Round 11
// 429.875 us; speedup vs baseline: 1.4695x; 1.1450x over previous
//
#include <hip/hip_runtime.h>
#include <hip/hip_bf16.h>
#include <cstddef>
#include <cstdint>

#define NM 50000
#define NA 50000
#define ND 500
#define FEAT 128
#define KDIM 768
#define BATCH 1024
#define NEDGE 1600000
#define MD 128            // ELL row capacity (deg ~ Poisson(32); P(>128) ~ 1e-38)

#define NBIN 196          // ceil(50000/256) node bins of 256 nodes
#define CAP 10240         // records per bin (expected 8163, 23 sigma headroom)
#define F1B 400           // fill_bin blocks
#define F1E (NEDGE / F1B) // 4000 edges per block (exact)

#define PBLK 391          // ceil(50000/128) blocks per big projection

typedef __bf16 bf16_t;
typedef bf16_t bf16x8 __attribute__((ext_vector_type(8)));
typedef bf16_t bf16x4 __attribute__((ext_vector_type(4)));
typedef float f32x4 __attribute__((ext_vector_type(4)));
typedef float f32x2 __attribute__((ext_vector_type(2)));
typedef unsigned short u16;
typedef unsigned char u8;

__device__ __forceinline__ float sigf(float x) { return 1.0f / (1.0f + __expf(-x)); }

// ---- fp8 e4m3 (OCP) helpers: HW v_cvt pack/unpack ----
__device__ __forceinline__ float4 dec4fp8(uint32_t w) {
  f32x2 lo = __builtin_amdgcn_cvt_pk_f32_fp8(w, false);
  f32x2 hi = __builtin_amdgcn_cvt_pk_f32_fp8(w, true);
  return make_float4(lo[0], lo[1], hi[0], hi[1]);
}
__device__ __forceinline__ u8 enc1fp8(float a) {
  return (u8)(__builtin_amdgcn_cvt_pk_fp8_f32(a, a, 0, false) & 0xff);
}

// ---------------- fill pass 1: edges -> bin-bucketed packed records -----------
__global__ __launch_bounds__(256) void fill_bin(
    const int* __restrict__ src, const int* __restrict__ dst,
    int* __restrict__ bcur, uint32_t* __restrict__ rec /* [2*NBIN][CAP] */)
{
  __shared__ uint32_t edg[F1E];      // 16 KB
  __shared__ int hist[2 * NBIN];
  __shared__ int base[2 * NBIN];
  const int tid = threadIdx.x;
  for (int i = tid; i < 2 * NBIN; i += 256) hist[i] = 0;
  __syncthreads();
  const int e0 = blockIdx.x * F1E;
  for (int i = tid; i < F1E; i += 256) {
    int s = __builtin_nontemporal_load(&src[e0 + i]);
    int d = __builtin_nontemporal_load(&dst[e0 + i]);
    edg[i] = ((uint32_t)s << 16) | (uint32_t)d;
    atomicAdd(&hist[s >> 8], 1);
    atomicAdd(&hist[NBIN + (d >> 8)], 1);
  }
  __syncthreads();
  for (int i = tid; i < 2 * NBIN; i += 256) {
    int c = hist[i];
    base[i] = c ? atomicAdd(&bcur[i], c) : 0;
    hist[i] = 0;  // reuse as emit cursor
  }
  __syncthreads();
  for (int i = tid; i < F1E; i += 256) {
    uint32_t e = edg[i];
    int s = (int)(e >> 16), d = (int)(e & 0xffffu);
    int bm = s >> 8, ba = NBIN + (d >> 8);
    int rm = base[bm] + atomicAdd(&hist[bm], 1);
    int ra = base[ba] + atomicAdd(&hist[ba], 1);
    if (rm < CAP) rec[(size_t)bm * CAP + rm] = e;
    if (ra < CAP) rec[(size_t)ba * CAP + ra] = ((uint32_t)d << 16) | (uint32_t)s;
  }
}

// ---------------- fill pass 2: records -> ELL rows + exact degrees ------------
__global__ __launch_bounds__(256) void fill_ell2(
    const uint32_t* __restrict__ rec, const int* __restrict__ bcur,
    u16* __restrict__ adjm, u16* __restrict__ adja,
    int* __restrict__ cnt_m, int* __restrict__ cnt_a)
{
  __shared__ int cnt256[256];
  const int g = blockIdx.x;                 // 0..2*NBIN-1
  const int side = g >= NBIN;
  const int bin = side ? g - NBIN : g;
  u16* adj = side ? adja : adjm;
  int* cnt = side ? cnt_a : cnt_m;
  cnt256[threadIdx.x] = 0;
  __syncthreads();
  int n = bcur[g]; if (n > CAP) n = CAP;
  const uint32_t* rb = rec + (size_t)g * CAP;
  for (int i = threadIdx.x; i < n; i += 256) {
    uint32_t r = rb[i];
    int node = (int)(r >> 16);
    int rk = atomicAdd(&cnt256[node & 255], 1);
    if (rk < MD) adj[(size_t)node * MD + rk] = (u16)(r & 0xffffu);
  }
  __syncthreads();
  int node = bin * 256 + threadIdx.x;
  if (node < NM) cnt[node] = cnt256[threadIdx.x];
}

// ---------------- util: 4x weight transpose->bf16 + deg->dinv ----------------
__global__ __launch_bounds__(256) void util_kernel(
    const float* __restrict__ W0, const float* __restrict__ W1,
    const float* __restrict__ W2, const float* __restrict__ W3,
    bf16_t* __restrict__ T0, bf16_t* __restrict__ T1,
    bf16_t* __restrict__ T2, bf16_t* __restrict__ T3,
    const int* __restrict__ cnt_m, const int* __restrict__ cnt_a,
    float* __restrict__ dm, float* __restrict__ da)
{
  const int b = blockIdx.x;
  if (b < 512) {
    const float* W = (b < 128) ? W0 : (b < 256) ? W1 : (b < 384) ? W2 : W3;
    bf16_t* T      = (b < 128) ? T0 : (b < 256) ? T1 : (b < 384) ? T2 : T3;
    int c = b & 127;
    for (int k = threadIdx.x; k < KDIM; k += 256)
      T[(size_t)c * KDIM + k] = (bf16_t)W[(size_t)k * FEAT + c];
  } else {
    int i = (b - 512) * 256 + threadIdx.x;
    if (i < NM) { int c = cnt_m[i]; dm[i] = c > 0 ? rsqrtf((float)c) : 0.f; }
    if (i < NA) { int c = cnt_a[i]; da[i] = c > 0 ? rsqrtf((float)c) : 0.f; }
  }
}

// ---------------- projection body: C = sigmoid(A[M,768] @ W + b) -------------
// OM: 0 = fp32 out, 2 = fp8(e4m3) out (row-scaled). C2: optional 0.25*sig bf16.
template<int OM>
__device__ __forceinline__ void proj_body(
    const float* __restrict__ A, const bf16_t* __restrict__ Wt,
    const float* __restrict__ bias, void* __restrict__ Cout, int M, int rowBase,
    const float* __restrict__ rowscale, bf16_t* __restrict__ C2)
{
  __shared__ bf16x8 sm[1024];  // [0..511]=A frags, [512..1023]=B frags
  const int tid = threadIdx.x;
  const int lane = tid & 63;
  const int wid = tid >> 6;

  f32x4 acc[4][4];
  #pragma unroll
  for (int m = 0; m < 4; ++m)
    #pragma unroll
    for (int n = 0; n < 4; ++n)
      acc[m][n] = (f32x4){0.f, 0.f, 0.f, 0.f};

  const int rl0 = ((tid >> 6) << 4) + (tid & 15);
  const int k8 = (tid >> 4) & 3;

  for (int k0 = 0; k0 < KDIM; k0 += 32) {
    #pragma unroll
    for (int i = 0; i < 2; ++i) {
      int rloc = rl0 + 64 * i;
      int rg = rowBase + rloc;
      if (rg > M - 1) rg = M - 1;
      const float* ap = A + (size_t)rg * KDIM + k0 + k8 * 8;
      float4 v0 = *(const float4*)ap;
      float4 v1 = *(const float4*)(ap + 4);
      bf16x8 w;
      w[0] = (bf16_t)v0.x; w[1] = (bf16_t)v0.y; w[2] = (bf16_t)v0.z; w[3] = (bf16_t)v0.w;
      w[4] = (bf16_t)v1.x; w[5] = (bf16_t)v1.y; w[6] = (bf16_t)v1.z; w[7] = (bf16_t)v1.w;
      sm[tid + i * 256] = w;
      sm[512 + tid + i * 256] = *(const bf16x8*)(Wt + (size_t)rloc * KDIM + k0 + k8 * 8);
    }
    __syncthreads();
    bf16x8 a[4], b[4];
    const int fm = (wid >> 1) * 4, fn = (wid & 1) * 4;
    #pragma unroll
    for (int m = 0; m < 4; ++m) a[m] = sm[(fm + m) * 64 + lane];
    #pragma unroll
    for (int n = 0; n < 4; ++n) b[n] = sm[512 + (fn + n) * 64 + lane];
    #pragma unroll
    for (int m = 0; m < 4; ++m)
      #pragma unroll
      for (int n = 0; n < 4; ++n)
        acc[m][n] = __builtin_amdgcn_mfma_f32_16x16x32_bf16(a[m], b[n], acc[m][n], 0, 0, 0);
    __syncthreads();
  }

  // C frag layout: col=lane&15, row=(lane>>4)*4+reg
  const int wRow = (wid >> 1) * 64, wCol = (wid & 1) * 64;
  const int r0 = (lane >> 4) * 4, cc = lane & 15;
  #pragma unroll
  for (int n = 0; n < 4; ++n) {
    int col = wCol + n * 16 + cc;
    float bb = bias[col];
    #pragma unroll
    for (int m = 0; m < 4; ++m) {
      #pragma unroll
      for (int r = 0; r < 4; ++r) {
        int row = rowBase + wRow + m * 16 + r0 + r;
        if (row < M) {
          float v = sigf(acc[m][n][r] + bb);
          float sc = rowscale ? rowscale[row] : 1.0f;
          if constexpr (OM == 2)
            ((u8*)Cout)[(size_t)row * FEAT + col] = enc1fp8(v * sc);
          else
            ((float*)Cout)[(size_t)row * FEAT + col] = v * sc;
          if (C2) C2[(size_t)row * FEAT + col] = (bf16_t)(0.25f * v);
        }
      }
    }
  }
}

// ---------------- ALL projections, one dispatch (798 blocks) ------------------
// blocks [0,391): mashup->M0y8(fp8,dm-scaled); [391,782): api->y0a8(fp8,da)+outA;
// [782,790): x->vmi; [790,794): domain->vkey; [794,798): domain->vval.
__global__ __launch_bounds__(256) void proj_all(
    const float* __restrict__ mashup, const float* __restrict__ api,
    const float* __restrict__ x, const float* __restrict__ domain,
    const bf16_t* __restrict__ wt0, const bf16_t* __restrict__ wt1,
    const bf16_t* __restrict__ wt2, const bf16_t* __restrict__ wt3,
    const float* __restrict__ bsde, const float* __restrict__ bkey,
    const float* __restrict__ bval, const float* __restrict__ bsie,
    u8* __restrict__ M0y8, u8* __restrict__ y0a8,
    float* __restrict__ vmi, float* __restrict__ vkey, float* __restrict__ vval,
    const float* __restrict__ dm, const float* __restrict__ da,
    bf16_t* __restrict__ outA)
{
  const int b = blockIdx.x;
  if (b < PBLK)
    proj_body<2>(mashup, wt0, bsde, M0y8, NM, b * 128, dm, nullptr);
  else if (b < 2 * PBLK)
    proj_body<2>(api, wt3, bsie, y0a8, NA, (b - PBLK) * 128, da, outA);
  else if (b < 2 * PBLK + 8)
    proj_body<0>(x, wt0, bsde, vmi, BATCH, (b - 2 * PBLK) * 128, nullptr, nullptr);
  else if (b < 2 * PBLK + 12)
    proj_body<0>(domain, wt1, bkey, vkey, ND, (b - 2 * PBLK - 8) * 128, nullptr, nullptr);
  else
    proj_body<0>(domain, wt2, bval, vval, ND, (b - 2 * PBLK - 12) * 128, nullptr, nullptr);
}

// ---------------- attention (phase-B split across both thread halves) ---------
__global__ __launch_bounds__(256) void attn_kernel(
    const float* __restrict__ vmi, const float* __restrict__ vkey,
    const float* __restrict__ vval, bf16_t* __restrict__ zm)
{
  const int i = blockIdx.x;
  const int tid = threadIdx.x;
  __shared__ float vs[FEAT];
  __shared__ float al[ND];
  __shared__ float red[4];
  __shared__ float ps[256];
  __shared__ float totS;
  if (tid < FEAT) vs[tid] = vmi[(size_t)i * FEAT + tid];
  __syncthreads();
  float part = 0.f;
  for (int j = tid; j < ND; j += 256) {
    const float* kr = vkey + (size_t)j * FEAT;
    float dot = 0.f;
    #pragma unroll 8
    for (int k = 0; k < FEAT; k += 4) {
      float4 kv = *(const float4*)(kr + k);
      dot += vs[k] * kv.x + vs[k + 1] * kv.y + vs[k + 2] * kv.z + vs[k + 3] * kv.w;
    }
    al[j] = dot;
    part += dot;
  }
  #pragma unroll
  for (int o = 32; o > 0; o >>= 1) part += __shfl_down(part, o, 64);
  if ((tid & 63) == 0) red[tid >> 6] = part;
  __syncthreads();
  if (tid == 0) totS = red[0] + red[1] + red[2] + red[3];
  // phase B: thread = (half h, feature f); each half sums 250 of the 500 rows
  const int f = tid & 127, h = tid >> 7;
  float s = 0.f;
  const float* vv = vval + (size_t)h * 250 * FEAT + f;
  #pragma unroll 5
  for (int j = 0; j < 250; ++j) s += al[h * 250 + j] * vv[(size_t)j * FEAT];
  ps[tid] = s;
  __syncthreads();
  if (tid < FEAT) {
    float z = 0.5f * ((ps[tid] + ps[128 + tid]) / totS + vs[tid]);
    zm[(size_t)i * FEAT + tid] = (bf16_t)z;
  }
}

// ---------------- fp8 row-gather: half-wave per alternate neighbor ------------
__device__ __forceinline__ float4 gatherF8(const uint32_t* __restrict__ base32,
                                           const u16* __restrict__ row,
                                           int n, int half)
{
  float4 acc = make_float4(0.f, 0.f, 0.f, 0.f);
  int j = half;
  while (j + 14 < n) {
    int u[8];
    #pragma unroll
    for (int q = 0; q < 8; ++q) u[q] = row[j + 2 * q];
    uint32_t w[8];
    #pragma unroll
    for (int q = 0; q < 8; ++q) w[q] = base32[(size_t)u[q] * 32];
    #pragma unroll
    for (int q = 0; q < 8; ++q) {
      float4 v = dec4fp8(w[q]);
      acc.x += v.x; acc.y += v.y; acc.z += v.z; acc.w += v.w;
    }
    j += 16;
  }
  while (j < n) {
    float4 v = dec4fp8(base32[(size_t)row[j] * 32]);
    acc.x += v.x; acc.y += v.y; acc.z += v.z; acc.w += v.w;
    j += 2;
  }
  return acc;
}

#define REDUCE_HALVES(acc)                    \
  acc.x += __shfl_xor(acc.x, 32);             \
  acc.y += __shfl_xor(acc.y, 32);             \
  acc.z += __shfl_xor(acc.z, 32);             \
  acc.w += __shfl_xor(acc.w, 32);

// ---- pass1 (api side): y01a = y0a + da^2 * sum_{m in N(a)} M0y[m] ------------
__global__ __launch_bounds__(256) void prop_p1(
    const uint32_t* __restrict__ M0y8, const uint32_t* __restrict__ y0a8,
    uint32_t* __restrict__ y01a8,
    const u16* __restrict__ adja, const int* __restrict__ cnt_a,
    const float* __restrict__ da)
{
  const int a = blockIdx.x * 4 + (threadIdx.x >> 6);
  const int lane = threadIdx.x & 63;
  const int half = lane >> 5, sl = lane & 31;
  int n = cnt_a[a]; if (n > MD) n = MD;
  float4 acc = gatherF8(M0y8 + sl, adja + (size_t)a * MD, n, half);
  REDUCE_HALVES(acc)
  if (half == 0) {
    const float d = da[a];
    const float s2 = d * d;
    float4 b = dec4fp8(y0a8[(size_t)a * 32 + sl]);
    uint32_t o = __builtin_amdgcn_cvt_pk_fp8_f32(b.x + s2 * acc.x, b.y + s2 * acc.y, 0, false);
    o = __builtin_amdgcn_cvt_pk_fp8_f32(b.z + s2 * acc.z, b.w + s2 * acc.w, o, true);
    y01a8[(size_t)a * 32 + sl] = o;
  }
}

// ---- pass2 (mashup side): Sy = M0y + dm^2 * sum_{a in N(m)} y01a[a] ----------
__global__ __launch_bounds__(256) void prop_p2(
    const uint32_t* __restrict__ y01a8, const uint32_t* __restrict__ M0y8,
    uint32_t* __restrict__ Sy8,
    const u16* __restrict__ adjm, const int* __restrict__ cnt_m,
    const float* __restrict__ dm)
{
  const int m = blockIdx.x * 4 + (threadIdx.x >> 6);
  const int lane = threadIdx.x & 63;
  const int half = lane >> 5, sl = lane & 31;
  int n = cnt_m[m]; if (n > MD) n = MD;
  float4 acc = gatherF8(y01a8 + sl, adjm + (size_t)m * MD, n, half);
  REDUCE_HALVES(acc)
  if (half == 0) {
    const float d = dm[m];
    const float s2 = d * d;
    float4 b = dec4fp8(M0y8[(size_t)m * 32 + sl]);
    uint32_t o = __builtin_amdgcn_cvt_pk_fp8_f32(b.x + s2 * acc.x, b.y + s2 * acc.y, 0, false);
    o = __builtin_amdgcn_cvt_pk_fp8_f32(b.z + s2 * acc.z, b.w + s2 * acc.w, o, true);
    Sy8[(size_t)m * 32 + sl] = o;
  }
}

// ---- pass3 (api side): O = 0.25*A0 + 0.25*da * sum_{m in N(a)} Sy[m] ---------
__global__ __launch_bounds__(256) void prop_p3(
    const uint32_t* __restrict__ Sy8, const bf16_t* __restrict__ outA,
    bf16_t* __restrict__ Obf,
    const u16* __restrict__ adja, const int* __restrict__ cnt_a,
    const float* __restrict__ da)
{
  const int a = blockIdx.x * 4 + (threadIdx.x >> 6);
  const int lane = threadIdx.x & 63;
  const int half = lane >> 5, sl = lane & 31;
  int n = cnt_a[a]; if (n > MD) n = MD;
  float4 acc = gatherF8(Sy8 + sl, adja + (size_t)a * MD, n, half);
  REDUCE_HALVES(acc)
  if (half == 0) {
    const float q = 0.25f * da[a];
    bf16x4 pv = *(const bf16x4*)(outA + (size_t)a * FEAT + 4 * sl);
    bf16x4 o;
    o[0] = (bf16_t)((float)pv[0] + q * acc.x);
    o[1] = (bf16_t)((float)pv[1] + q * acc.y);
    o[2] = (bf16_t)((float)pv[2] + q * acc.z);
    o[3] = (bf16_t)((float)pv[3] + q * acc.w);
    *(bf16x4*)(Obf + (size_t)a * FEAT + 4 * sl) = o;
  }
}

// ---------------- pred = Z[1024,128] @ O[50000,128]^T, bf16 MFMA --------------
__global__ __launch_bounds__(256) void pred_mfma(
    const bf16_t* __restrict__ Z, const bf16_t* __restrict__ O,
    float* __restrict__ out)
{
  const int lane = threadIdx.x & 63;
  const int wid = threadIdx.x >> 6;
  const int nBase = blockIdx.x * 256 + wid * 64;
  const int cc = lane & 15;
  const int kOff = (lane >> 4) * 8;

  bf16x8 b[4][4];
  #pragma unroll
  for (int n = 0; n < 4; ++n) {
    int c = nBase + n * 16 + cc;
    if (c > NA - 1) c = NA - 1;
    #pragma unroll
    for (int kk = 0; kk < 4; ++kk)
      b[n][kk] = *(const bf16x8*)(O + (size_t)c * FEAT + kk * 32 + kOff);
  }

  const int r0 = (lane >> 4) * 4;
  #pragma unroll
  for (int it = 0; it < 4; ++it) {
    const int iBase = blockIdx.y * 256 + it * 64;
    f32x4 acc[4][4];
    #pragma unroll
    for (int m = 0; m < 4; ++m)
      #pragma unroll
      for (int n = 0; n < 4; ++n)
        acc[m][n] = (f32x4){0.f, 0.f, 0.f, 0.f};

    #pragma unroll
    for (int kk = 0; kk < 4; ++kk) {
      bf16x8 a[4];
      #pragma unroll
      for (int m = 0; m < 4; ++m)
        a[m] = *(const bf16x8*)(Z + (size_t)(iBase + cc + m * 16) * FEAT + kk * 32 + kOff);
      #pragma unroll
      for (int m = 0; m < 4; ++m)
        #pragma unroll
        for (int n = 0; n < 4; ++n)
          acc[m][n] = __builtin_amdgcn_mfma_f32_16x16x32_bf16(a[m], b[n][kk], acc[m][n], 0, 0, 0);
    }

    #pragma unroll
    for (int n = 0; n < 4; ++n) {
      int col = nBase + n * 16 + cc;
      if (col < NA) {
        #pragma unroll
        for (int m = 0; m < 4; ++m) {
          #pragma unroll
          for (int r = 0; r < 4; ++r) {
            int row = iBase + m * 16 + r0 + r;
            __builtin_nontemporal_store(acc[m][n][r], &out[(size_t)row * NA + col]);
          }
        }
      }
    }
  }
}

static inline char* alignup(char* p, size_t a) {
  return (char*)(((uintptr_t)p + a - 1) & ~(uintptr_t)(a - 1));
}

extern "C" void kernel_launch(void* const* d_in, const int* in_sizes, int n_in,
                              void* d_out, int out_size, void* d_ws, size_t ws_size,
                              hipStream_t stream) {
  const float* x      = (const float*)d_in[0];
  const float* mashup = (const float*)d_in[1];
  const float* domain = (const float*)d_in[2];
  const float* api    = (const float*)d_in[3];
  const float* Wsde   = (const float*)d_in[4];
  const float* bsde   = (const float*)d_in[5];
  const float* Wval   = (const float*)d_in[6];
  const float* bval   = (const float*)d_in[7];
  const float* Wkey   = (const float*)d_in[8];
  const float* bkey   = (const float*)d_in[9];
  const float* Wsie   = (const float*)d_in[10];
  const float* bsie   = (const float*)d_in[11];
  const int* esrc     = (const int*)d_in[12];
  const int* edst     = (const int*)d_in[13];
  float* out = (float*)d_out;

  // workspace layout (~90 MB)
  char* p = (char*)d_ws;
  u8*     M0y8  = (u8*)p; p += (size_t)NM * FEAT;                 // 6.4MB
  u8*     y0a8  = (u8*)p; p += (size_t)NA * FEAT;                 // 6.4MB
  u8*     y01a8 = (u8*)p; p += (size_t)NA * FEAT;                 // 6.4MB
  u8*     Sy8   = (u8*)p; p += (size_t)NM * FEAT;                 // 6.4MB
  bf16_t* outA  = (bf16_t*)p; p += (size_t)NA * FEAT * 2;         // 12.8MB
  bf16_t* Obf   = (bf16_t*)p; p += (size_t)NA * FEAT * 2;         // 12.8MB
  u16*    adjm  = (u16*)p;    p += (size_t)NM * MD * 2;           // 12.8MB
  u16*    adja  = (u16*)p;    p += (size_t)NA * MD * 2;           // 12.8MB
  float*  vmi   = (float*)p;  p += (size_t)BATCH * FEAT * 4;
  float*  vkey  = (float*)p;  p += (size_t)ND * FEAT * 4;
  float*  vval  = (float*)p;  p += (size_t)ND * FEAT * 4;
  bf16_t* zm    = (bf16_t*)p; p += (size_t)BATCH * FEAT * 2;
  int* cnt_m = (int*)p; p += (size_t)NM * 4;
  int* cnt_a = (int*)p; p += (size_t)NA * 4;
  float* dm  = (float*)p; p += (size_t)NM * 4;
  float* da  = (float*)p; p += (size_t)NA * 4;
  int* bcur  = (int*)p; p += 512 * 4;
  p = alignup(p, 16);
  bf16_t* wt0 = (bf16_t*)p; p += (size_t)FEAT * KDIM * 2;
  bf16_t* wt1 = (bf16_t*)p; p += (size_t)FEAT * KDIM * 2;
  bf16_t* wt2 = (bf16_t*)p; p += (size_t)FEAT * KDIM * 2;
  bf16_t* wt3 = (bf16_t*)p; p += (size_t)FEAT * KDIM * 2;
  // rec (2*NBIN*CAP*4B = 16.1MB) overlays M0y8+y0a8+y01a8 (19.2MB): dead
  // before proj_all/prop write those (fill_ell2 completes first, same stream).
  uint32_t* rec = (uint32_t*)M0y8;

  hipMemsetAsync(bcur, 0, 512 * sizeof(int), stream);

  // ---- graph build: two-level binning (157K global atomics vs 3.2M) ----
  fill_bin<<<F1B, 256, 0, stream>>>(esrc, edst, bcur, rec);
  fill_ell2<<<2 * NBIN, 256, 0, stream>>>(rec, bcur, adjm, adja, cnt_m, cnt_a);
  util_kernel<<<512 + (NM + 255) / 256, 256, 0, stream>>>(
      Wsde, Wkey, Wval, Wsie, wt0, wt1, wt2, wt3, cnt_m, cnt_a, dm, da);

  // ---- ALL projections in one dispatch (798 blocks) ----
  proj_all<<<2 * PBLK + 16, 256, 0, stream>>>(
      mashup, api, x, domain, wt0, wt1, wt2, wt3,
      bsde, bkey, bval, bsie, M0y8, y0a8, vmi, vkey, vval, dm, da, outA);

  attn_kernel<<<BATCH, 256, 0, stream>>>(vmi, vkey, vval, zm);

  // ---- bipartite LightGCN (fp8 gathers): out_api = 0.25*(A0 + P^T(M0+M1+M2)) ----
  prop_p1<<<NA / 4, 256, 0, stream>>>((const uint32_t*)M0y8, (const uint32_t*)y0a8,
                                      (uint32_t*)y01a8, adja, cnt_a, da);
  prop_p2<<<NM / 4, 256, 0, stream>>>((const uint32_t*)y01a8, (const uint32_t*)M0y8,
                                      (uint32_t*)Sy8, adjm, cnt_m, dm);
  prop_p3<<<NA / 4, 256, 0, stream>>>((const uint32_t*)Sy8, outA, Obf,
                                      adja, cnt_a, da);

  pred_mfma<<<dim3((NA + 255) / 256, BATCH / 256), 256, 0, stream>>>(zm, Obf, out);
}

// Round 12
// 421.282 us; speedup vs baseline: 1.4995x; 1.0204x over previous
//
#include <hip/hip_runtime.h>
#include <hip/hip_bf16.h>
#include <cstddef>
#include <cstdint>

#define NM 50000
#define NA 50000
#define ND 500
#define FEAT 128
#define KDIM 768
#define BATCH 1024
#define NEDGE 1600000
#define MD 128            // ELL row capacity (deg ~ Poisson(32); P(>128) ~ 1e-38)

#define NBIN 196          // ceil(50000/256) node bins of 256 nodes
#define CAP 10240         // records per bin (expected 8163, 23 sigma headroom)
#define F1B 400           // fill_bin blocks
#define F1E (NEDGE / F1B) // 4000 edges per block (exact)

#define PB64 782          // ceil(50000/64) blocks per big projection (BM=64)

typedef __bf16 bf16_t;
typedef bf16_t bf16x8 __attribute__((ext_vector_type(8)));
typedef bf16_t bf16x4 __attribute__((ext_vector_type(4)));
typedef float f32x4 __attribute__((ext_vector_type(4)));
typedef float f32x2 __attribute__((ext_vector_type(2)));
typedef unsigned short u16;
typedef unsigned char u8;

__device__ __forceinline__ float sigf(float x) { return 1.0f / (1.0f + __expf(-x)); }

// ---- fp8 e4m3 (OCP) helpers: HW v_cvt pack/unpack ----
__device__ __forceinline__ float4 dec4fp8(uint32_t w) {
  f32x2 lo = __builtin_amdgcn_cvt_pk_f32_fp8(w, false);
  f32x2 hi = __builtin_amdgcn_cvt_pk_f32_fp8(w, true);
  return make_float4(lo[0], lo[1], hi[0], hi[1]);
}
__device__ __forceinline__ u8 enc1fp8(float a) {
  return (u8)(__builtin_amdgcn_cvt_pk_fp8_f32(a, a, 0, false) & 0xff);
}

// ---------------- fill pass 1: edges -> bin-bucketed packed records -----------
__global__ __launch_bounds__(256) void fill_bin(
    const int* __restrict__ src, const int* __restrict__ dst,
    int* __restrict__ bcur, uint32_t* __restrict__ rec /* [2*NBIN][CAP] */)
{
  __shared__ uint32_t edg[F1E];      // 16 KB
  __shared__ int hist[2 * NBIN];
  __shared__ int base[2 * NBIN];
  const int tid = threadIdx.x;
  for (int i = tid; i < 2 * NBIN; i += 256) hist[i] = 0;
  __syncthreads();
  const int e0 = blockIdx.x * F1E;
  for (int i = tid; i < F1E; i += 256) {
    int s = __builtin_nontemporal_load(&src[e0 + i]);
    int d = __builtin_nontemporal_load(&dst[e0 + i]);
    edg[i] = ((uint32_t)s << 16) | (uint32_t)d;
    atomicAdd(&hist[s >> 8], 1);
    atomicAdd(&hist[NBIN + (d >> 8)], 1);
  }
  __syncthreads();
  for (int i = tid; i < 2 * NBIN; i += 256) {
    int c = hist[i];
    base[i] = c ? atomicAdd(&bcur[i], c) : 0;
    hist[i] = 0;  // reuse as emit cursor
  }
  __syncthreads();
  for (int i = tid; i < F1E; i += 256) {
    uint32_t e = edg[i];
    int s = (int)(e >> 16), d = (int)(e & 0xffffu);
    int bm = s >> 8, ba = NBIN + (d >> 8);
    int rm = base[bm] + atomicAdd(&hist[bm], 1);
    int ra = base[ba] + atomicAdd(&hist[ba], 1);
    if (rm < CAP) rec[(size_t)bm * CAP + rm] = e;
    if (ra < CAP) rec[(size_t)ba * CAP + ra] = ((uint32_t)d << 16) | (uint32_t)s;
  }
}

// ---------------- fill pass 2: records -> ELL rows + exact degrees ------------
__global__ __launch_bounds__(256) void fill_ell2(
    const uint32_t* __restrict__ rec, const int* __restrict__ bcur,
    u16* __restrict__ adjm, u16* __restrict__ adja,
    int* __restrict__ cnt_m, int* __restrict__ cnt_a)
{
  __shared__ int cnt256[256];
  const int g = blockIdx.x;                 // 0..2*NBIN-1
  const int side = g >= NBIN;
  const int bin = side ? g - NBIN : g;
  u16* adj = side ? adja : adjm;
  int* cnt = side ? cnt_a : cnt_m;
  cnt256[threadIdx.x] = 0;
  __syncthreads();
  int n = bcur[g]; if (n > CAP) n = CAP;
  const uint32_t* rb = rec + (size_t)g * CAP;
  for (int i = threadIdx.x; i < n; i += 256) {
    uint32_t r = rb[i];
    int node = (int)(r >> 16);
    int rk = atomicAdd(&cnt256[node & 255], 1);
    if (rk < MD) adj[(size_t)node * MD + rk] = (u16)(r & 0xffffu);
  }
  __syncthreads();
  int node = bin * 256 + threadIdx.x;
  if (node < NM) cnt[node] = cnt256[threadIdx.x];
}

// ---------------- util: 4x weight transpose->bf16 + deg->dinv ----------------
__global__ __launch_bounds__(256) void util_kernel(
    const float* __restrict__ W0, const float* __restrict__ W1,
    const float* __restrict__ W2, const float* __restrict__ W3,
    bf16_t* __restrict__ T0, bf16_t* __restrict__ T1,
    bf16_t* __restrict__ T2, bf16_t* __restrict__ T3,
    const int* __restrict__ cnt_m, const int* __restrict__ cnt_a,
    float* __restrict__ dm, float* __restrict__ da)
{
  const int b = blockIdx.x;
  if (b < 512) {
    const float* W = (b < 128) ? W0 : (b < 256) ? W1 : (b < 384) ? W2 : W3;
    bf16_t* T      = (b < 128) ? T0 : (b < 256) ? T1 : (b < 384) ? T2 : T3;
    int c = b & 127;
    for (int k = threadIdx.x; k < KDIM; k += 256)
      T[(size_t)c * KDIM + k] = (bf16_t)W[(size_t)k * FEAT + c];
  } else {
    int i = (b - 512) * 256 + threadIdx.x;
    if (i < NM) { int c = cnt_m[i]; dm[i] = c > 0 ? rsqrtf((float)c) : 0.f; }
    if (i < NA) { int c = cnt_a[i]; da[i] = c > 0 ? rsqrtf((float)c) : 0.f; }
  }
}

// ---------------- projection body, BM=64, reg-pipelined -----------------------
// C = sigmoid(A[M,768] @ W + b). OM: 0 = fp32 out, 2 = fp8 out (row-scaled).
// 4 waves (2x2), wave tile 32x64 (2x4 frags of 16x16x32). K-tile t+1's global
// loads are issued while tile t's MFMAs run (reg software pipeline).
template<int OM>
__device__ __forceinline__ void proj_body(
    const float* __restrict__ A, const bf16_t* __restrict__ Wt,
    const float* __restrict__ bias, void* __restrict__ Cout, int M, int rowBase,
    const float* __restrict__ rowscale, bf16_t* __restrict__ C2)
{
  __shared__ bf16x8 sm[768];  // [0..255]=A frags (4x16 rows), [256..767]=B frags (8x16 cols)
  const int tid = threadIdx.x;
  const int lane = tid & 63;
  const int wid = tid >> 6;

  f32x4 acc[2][4];
  #pragma unroll
  for (int m = 0; m < 2; ++m)
    #pragma unroll
    for (int n = 0; n < 4; ++n)
      acc[m][n] = (f32x4){0.f, 0.f, 0.f, 0.f};

  // staging coords: thread t stages A slot t (row arow, k-group k8) and
  // B slots t, t+256 (cols arow, arow+64).
  const int arow = ((tid >> 6) << 4) + (tid & 15);   // [0,64)
  const int k8 = (tid >> 4) & 3;
  int arg = rowBase + arow; if (arg > M - 1) arg = M - 1;
  const float*  aptr  = A  + (size_t)arg * KDIM + k8 * 8;
  const bf16_t* bptr0 = Wt + (size_t)arow * KDIM + k8 * 8;
  const bf16_t* bptr1 = Wt + (size_t)(arow + 64) * KDIM + k8 * 8;

  float4 pa0 = *(const float4*)aptr;
  float4 pa1 = *(const float4*)(aptr + 4);
  bf16x8 pb0 = *(const bf16x8*)bptr0;
  bf16x8 pb1 = *(const bf16x8*)bptr1;

  const int fm0 = (wid >> 1) * 2, fn0 = (wid & 1) * 4;

  for (int kt = 0; kt < KDIM / 32; ++kt) {
    bf16x8 w;
    w[0] = (bf16_t)pa0.x; w[1] = (bf16_t)pa0.y; w[2] = (bf16_t)pa0.z; w[3] = (bf16_t)pa0.w;
    w[4] = (bf16_t)pa1.x; w[5] = (bf16_t)pa1.y; w[6] = (bf16_t)pa1.z; w[7] = (bf16_t)pa1.w;
    sm[tid] = w;
    sm[256 + tid] = pb0;
    sm[512 + tid] = pb1;
    __syncthreads();
    if (kt + 1 < KDIM / 32) {          // prefetch next K-tile (overlaps MFMA below)
      const int ko = (kt + 1) * 32;
      pa0 = *(const float4*)(aptr + ko);
      pa1 = *(const float4*)(aptr + ko + 4);
      pb0 = *(const bf16x8*)(bptr0 + ko);
      pb1 = *(const bf16x8*)(bptr1 + ko);
    }
    bf16x8 a[2], b[4];
    #pragma unroll
    for (int m = 0; m < 2; ++m) a[m] = sm[(fm0 + m) * 64 + lane];
    #pragma unroll
    for (int n = 0; n < 4; ++n) b[n] = sm[256 + (fn0 + n) * 64 + lane];
    #pragma unroll
    for (int m = 0; m < 2; ++m)
      #pragma unroll
      for (int n = 0; n < 4; ++n)
        acc[m][n] = __builtin_amdgcn_mfma_f32_16x16x32_bf16(a[m], b[n], acc[m][n], 0, 0, 0);
    __syncthreads();
  }

  // C frag layout: col=lane&15, row=(lane>>4)*4+reg
  const int wRow = (wid >> 1) * 32, wCol = (wid & 1) * 64;
  const int r0 = (lane >> 4) * 4, cc = lane & 15;
  #pragma unroll
  for (int n = 0; n < 4; ++n) {
    int col = wCol + n * 16 + cc;
    float bb = bias[col];
    #pragma unroll
    for (int m = 0; m < 2; ++m) {
      #pragma unroll
      for (int r = 0; r < 4; ++r) {
        int row = rowBase + wRow + m * 16 + r0 + r;
        if (row < M) {
          float v = sigf(acc[m][n][r] + bb);
          float sc = rowscale ? rowscale[row] : 1.0f;
          if constexpr (OM == 2)
            ((u8*)Cout)[(size_t)row * FEAT + col] = enc1fp8(v * sc);
          else
            ((float*)Cout)[(size_t)row * FEAT + col] = v * sc;
          if (C2) C2[(size_t)row * FEAT + col] = (bf16_t)(0.25f * v);
        }
      }
    }
  }
}

// ---------------- ALL projections, one dispatch (1596 blocks, BM=64) ----------
// [0,782): mashup->M0y8(fp8,dm); [782,1564): api->y0a8(fp8,da)+outA;
// [1564,1580): x->vmi; [1580,1588): domain->vkey; [1588,1596): domain->vval.
__global__ __launch_bounds__(256) void proj_all(
    const float* __restrict__ mashup, const float* __restrict__ api,
    const float* __restrict__ x, const float* __restrict__ domain,
    const bf16_t* __restrict__ wt0, const bf16_t* __restrict__ wt1,
    const bf16_t* __restrict__ wt2, const bf16_t* __restrict__ wt3,
    const float* __restrict__ bsde, const float* __restrict__ bkey,
    const float* __restrict__ bval, const float* __restrict__ bsie,
    u8* __restrict__ M0y8, u8* __restrict__ y0a8,
    float* __restrict__ vmi, float* __restrict__ vkey, float* __restrict__ vval,
    const float* __restrict__ dm, const float* __restrict__ da,
    bf16_t* __restrict__ outA)
{
  const int b = blockIdx.x;
  if (b < PB64)
    proj_body<2>(mashup, wt0, bsde, M0y8, NM, b * 64, dm, nullptr);
  else if (b < 2 * PB64)
    proj_body<2>(api, wt3, bsie, y0a8, NA, (b - PB64) * 64, da, outA);
  else if (b < 2 * PB64 + 16)
    proj_body<0>(x, wt0, bsde, vmi, BATCH, (b - 2 * PB64) * 64, nullptr, nullptr);
  else if (b < 2 * PB64 + 24)
    proj_body<0>(domain, wt1, bkey, vkey, ND, (b - 2 * PB64 - 16) * 64, nullptr, nullptr);
  else
    proj_body<0>(domain, wt2, bval, vval, ND, (b - 2 * PB64 - 24) * 64, nullptr, nullptr);
}

// ---------------- attention (phase-B split across both thread halves) ---------
__global__ __launch_bounds__(256) void attn_kernel(
    const float* __restrict__ vmi, const float* __restrict__ vkey,
    const float* __restrict__ vval, bf16_t* __restrict__ zm)
{
  const int i = blockIdx.x;
  const int tid = threadIdx.x;
  __shared__ float vs[FEAT];
  __shared__ float al[ND];
  __shared__ float red[4];
  __shared__ float ps[256];
  __shared__ float totS;
  if (tid < FEAT) vs[tid] = vmi[(size_t)i * FEAT + tid];
  __syncthreads();
  float part = 0.f;
  for (int j = tid; j < ND; j += 256) {
    const float* kr = vkey + (size_t)j * FEAT;
    float dot = 0.f;
    #pragma unroll 8
    for (int k = 0; k < FEAT; k += 4) {
      float4 kv = *(const float4*)(kr + k);
      dot += vs[k] * kv.x + vs[k + 1] * kv.y + vs[k + 2] * kv.z + vs[k + 3] * kv.w;
    }
    al[j] = dot;
    part += dot;
  }
  #pragma unroll
  for (int o = 32; o > 0; o >>= 1) part += __shfl_down(part, o, 64);
  if ((tid & 63) == 0) red[tid >> 6] = part;
  __syncthreads();
  if (tid == 0) totS = red[0] + red[1] + red[2] + red[3];
  // phase B: thread = (half h, feature f); each half sums 250 of the 500 rows
  const int f = tid & 127, h = tid >> 7;
  float s = 0.f;
  const float* vv = vval + (size_t)h * 250 * FEAT + f;
  #pragma unroll 5
  for (int j = 0; j < 250; ++j) s += al[h * 250 + j] * vv[(size_t)j * FEAT];
  ps[tid] = s;
  __syncthreads();
  if (tid < FEAT) {
    float z = 0.5f * ((ps[tid] + ps[128 + tid]) / totS + vs[tid]);
    zm[(size_t)i * FEAT + tid] = (bf16_t)z;
  }
}

// ---------------- fp8 row-gather: half-wave per alternate neighbor ------------
__device__ __forceinline__ float4 gatherF8(const uint32_t* __restrict__ base32,
                                           const u16* __restrict__ row,
                                           int n, int half)
{
  float4 acc = make_float4(0.f, 0.f, 0.f, 0.f);
  int j = half;
  while (j + 14 < n) {
    int u[8];
    #pragma unroll
    for (int q = 0; q < 8; ++q) u[q] = row[j + 2 * q];
    uint32_t w[8];
    #pragma unroll
    for (int q = 0; q < 8; ++q) w[q] = base32[(size_t)u[q] * 32];
    #pragma unroll
    for (int q = 0; q < 8; ++q) {
      float4 v = dec4fp8(w[q]);
      acc.x += v.x; acc.y += v.y; acc.z += v.z; acc.w += v.w;
    }
    j += 16;
  }
  while (j < n) {
    float4 v = dec4fp8(base32[(size_t)row[j] * 32]);
    acc.x += v.x; acc.y += v.y; acc.z += v.z; acc.w += v.w;
    j += 2;
  }
  return acc;
}

#define REDUCE_HALVES(acc)                    \
  acc.x += __shfl_xor(acc.x, 32);             \
  acc.y += __shfl_xor(acc.y, 32);             \
  acc.z += __shfl_xor(acc.z, 32);             \
  acc.w += __shfl_xor(acc.w, 32);

// ---- pass1 (api side): y01a = y0a + da^2 * sum_{m in N(a)} M0y[m] ------------
__global__ __launch_bounds__(256) void prop_p1(
    const uint32_t* __restrict__ M0y8, const uint32_t* __restrict__ y0a8,
    uint32_t* __restrict__ y01a8,
    const u16* __restrict__ adja, const int* __restrict__ cnt_a,
    const float* __restrict__ da)
{
  const int a = blockIdx.x * 4 + (threadIdx.x >> 6);
  const int lane = threadIdx.x & 63;
  const int half = lane >> 5, sl = lane & 31;
  int n = cnt_a[a]; if (n > MD) n = MD;
  float4 acc = gatherF8(M0y8 + sl, adja + (size_t)a * MD, n, half);
  REDUCE_HALVES(acc)
  if (half == 0) {
    const float d = da[a];
    const float s2 = d * d;
    float4 b = dec4fp8(y0a8[(size_t)a * 32 + sl]);
    uint32_t o = __builtin_amdgcn_cvt_pk_fp8_f32(b.x + s2 * acc.x, b.y + s2 * acc.y, 0, false);
    o = __builtin_amdgcn_cvt_pk_fp8_f32(b.z + s2 * acc.z, b.w + s2 * acc.w, o, true);
    y01a8[(size_t)a * 32 + sl] = o;
  }
}

// ---- pass2 (mashup side): Sy = M0y + dm^2 * sum_{a in N(m)} y01a[a] ----------
__global__ __launch_bounds__(256) void prop_p2(
    const uint32_t* __restrict__ y01a8, const uint32_t* __restrict__ M0y8,
    uint32_t* __restrict__ Sy8,
    const u16* __restrict__ adjm, const int* __restrict__ cnt_m,
    const float* __restrict__ dm)
{
  const int m = blockIdx.x * 4 + (threadIdx.x >> 6);
  const int lane = threadIdx.x & 63;
  const int half = lane >> 5, sl = lane & 31;
  int n = cnt_m[m]; if (n > MD) n = MD;
  float4 acc = gatherF8(y01a8 + sl, adjm + (size_t)m * MD, n, half);
  REDUCE_HALVES(acc)
  if (half == 0) {
    const float d = dm[m];
    const float s2 = d * d;
    float4 b = dec4fp8(M0y8[(size_t)m * 32 + sl]);
    uint32_t o = __builtin_amdgcn_cvt_pk_fp8_f32(b.x + s2 * acc.x, b.y + s2 * acc.y, 0, false);
    o = __builtin_amdgcn_cvt_pk_fp8_f32(b.z + s2 * acc.z, b.w + s2 * acc.w, o, true);
    Sy8[(size_t)m * 32 + sl] = o;
  }
}

// ---- pass3 (api side): O = 0.25*A0 + 0.25*da * sum_{m in N(a)} Sy[m] ---------
__global__ __launch_bounds__(256) void prop_p3(
    const uint32_t* __restrict__ Sy8, const bf16_t* __restrict__ outA,
    bf16_t* __restrict__ Obf,
    const u16* __restrict__ adja, const int* __restrict__ cnt_a,
    const float* __restrict__ da)
{
  const int a = blockIdx.x * 4 + (threadIdx.x >> 6);
  const int lane = threadIdx.x & 63;
  const int half = lane >> 5, sl = lane & 31;
  int n = cnt_a[a]; if (n > MD) n = MD;
  float4 acc = gatherF8(Sy8 + sl, adja + (size_t)a * MD, n, half);
  REDUCE_HALVES(acc)
  if (half == 0) {
    const float q = 0.25f * da[a];
    bf16x4 pv = *(const bf16x4*)(outA + (size_t)a * FEAT + 4 * sl);
    bf16x4 o;
    o[0] = (bf16_t)((float)pv[0] + q * acc.x);
    o[1] = (bf16_t)((float)pv[1] + q * acc.y);
    o[2] = (bf16_t)((float)pv[2] + q * acc.z);
    o[3] = (bf16_t)((float)pv[3] + q * acc.w);
    *(bf16x4*)(Obf + (size_t)a * FEAT + 4 * sl) = o;
  }
}

// ---------------- pred = Z[1024,128] @ O[50000,128]^T, bf16 MFMA --------------
__global__ __launch_bounds__(256) void pred_mfma(
    const bf16_t* __restrict__ Z, const bf16_t* __restrict__ O,
    float* __restrict__ out)
{
  const int lane = threadIdx.x & 63;
  const int wid = threadIdx.x >> 6;
  const int nBase = blockIdx.x * 256 + wid * 64;
  const int cc = lane & 15;
  const int kOff = (lane >> 4) * 8;

  bf16x8 b[4][4];
  #pragma unroll
  for (int n = 0; n < 4; ++n) {
    int c = nBase + n * 16 + cc;
    if (c > NA - 1) c = NA - 1;
    #pragma unroll
    for (int kk = 0; kk < 4; ++kk)
      b[n][kk] = *(const bf16x8*)(O + (size_t)c * FEAT + kk * 32 + kOff);
  }

  const int r0 = (lane >> 4) * 4;
  #pragma unroll
  for (int it = 0; it < 4; ++it) {
    const int iBase = blockIdx.y * 256 + it * 64;
    f32x4 acc[4][4];
    #pragma unroll
    for (int m = 0; m < 4; ++m)
      #pragma unroll
      for (int n = 0; n < 4; ++n)
        acc[m][n] = (f32x4){0.f, 0.f, 0.f, 0.f};

    #pragma unroll
    for (int kk = 0; kk < 4; ++kk) {
      bf16x8 a[4];
      #pragma unroll
      for (int m = 0; m < 4; ++m)
        a[m] = *(const bf16x8*)(Z + (size_t)(iBase + cc + m * 16) * FEAT + kk * 32 + kOff);
      #pragma unroll
      for (int m = 0; m < 4; ++m)
        #pragma unroll
        for (int n = 0; n < 4; ++n)
          acc[m][n] = __builtin_amdgcn_mfma_f32_16x16x32_bf16(a[m], b[n][kk], acc[m][n], 0, 0, 0);
    }

    #pragma unroll
    for (int n = 0; n < 4; ++n) {
      int col = nBase + n * 16 + cc;
      if (col < NA) {
        #pragma unroll
        for (int m = 0; m < 4; ++m) {
          #pragma unroll
          for (int r = 0; r < 4; ++r) {
            int row = iBase + m * 16 + r0 + r;
            __builtin_nontemporal_store(acc[m][n][r], &out[(size_t)row * NA + col]);
          }
        }
      }
    }
  }
}

static inline char* alignup(char* p, size_t a) {
  return (char*)(((uintptr_t)p + a - 1) & ~(uintptr_t)(a - 1));
}

extern "C" void kernel_launch(void* const* d_in, const int* in_sizes, int n_in,
                              void* d_out, int out_size, void* d_ws, size_t ws_size,
                              hipStream_t stream) {
  const float* x      = (const float*)d_in[0];
  const float* mashup = (const float*)d_in[1];
  const float* domain = (const float*)d_in[2];
  const float* api    = (const float*)d_in[3];
  const float* Wsde   = (const float*)d_in[4];
  const float* bsde   = (const float*)d_in[5];
  const float* Wval   = (const float*)d_in[6];
  const float* bval   = (const float*)d_in[7];
  const float* Wkey   = (const float*)d_in[8];
  const float* bkey   = (const float*)d_in[9];
  const float* Wsie   = (const float*)d_in[10];
  const float* bsie   = (const float*)d_in[11];
  const int* esrc     = (const int*)d_in[12];
  const int* edst     = (const int*)d_in[13];
  float* out = (float*)d_out;

  // workspace layout (~90 MB)
  char* p = (char*)d_ws;
  u8*     M0y8  = (u8*)p; p += (size_t)NM * FEAT;                 // 6.4MB
  u8*     y0a8  = (u8*)p; p += (size_t)NA * FEAT;                 // 6.4MB
  u8*     y01a8 = (u8*)p; p += (size_t)NA * FEAT;                 // 6.4MB
  u8*     Sy8   = (u8*)p; p += (size_t)NM * FEAT;                 // 6.4MB
  bf16_t* outA  = (bf16_t*)p; p += (size_t)NA * FEAT * 2;         // 12.8MB
  bf16_t* Obf   = (bf16_t*)p; p += (size_t)NA * FEAT * 2;         // 12.8MB
  u16*    adjm  = (u16*)p;    p += (size_t)NM * MD * 2;           // 12.8MB
  u16*    adja  = (u16*)p;    p += (size_t)NA * MD * 2;           // 12.8MB
  float*  vmi   = (float*)p;  p += (size_t)BATCH * FEAT * 4;
  float*  vkey  = (float*)p;  p += (size_t)ND * FEAT * 4;
  float*  vval  = (float*)p;  p += (size_t)ND * FEAT * 4;
  bf16_t* zm    = (bf16_t*)p; p += (size_t)BATCH * FEAT * 2;
  int* cnt_m = (int*)p; p += (size_t)NM * 4;
  int* cnt_a = (int*)p; p += (size_t)NA * 4;
  float* dm  = (float*)p; p += (size_t)NM * 4;
  float* da  = (float*)p; p += (size_t)NA * 4;
  int* bcur  = (int*)p; p += 512 * 4;
  p = alignup(p, 16);
  bf16_t* wt0 = (bf16_t*)p; p += (size_t)FEAT * KDIM * 2;
  bf16_t* wt1 = (bf16_t*)p; p += (size_t)FEAT * KDIM * 2;
  bf16_t* wt2 = (bf16_t*)p; p += (size_t)FEAT * KDIM * 2;
  bf16_t* wt3 = (bf16_t*)p; p += (size_t)FEAT * KDIM * 2;
  // rec (2*NBIN*CAP*4B = 16.1MB) overlays M0y8+y0a8+y01a8 (19.2MB): dead
  // before proj_all/prop write those (fill_ell2 completes first, same stream).
  uint32_t* rec = (uint32_t*)M0y8;

  hipMemsetAsync(bcur, 0, 512 * sizeof(int), stream);

  // ---- graph build: two-level binning (157K global atomics vs 3.2M) ----
  fill_bin<<<F1B, 256, 0, stream>>>(esrc, edst, bcur, rec);
  fill_ell2<<<2 * NBIN, 256, 0, stream>>>(rec, bcur, adjm, adja, cnt_m, cnt_a);
  util_kernel<<<512 + (NM + 255) / 256, 256, 0, stream>>>(
      Wsde, Wkey, Wval, Wsie, wt0, wt1, wt2, wt3, cnt_m, cnt_a, dm, da);

  // ---- ALL projections in one dispatch (1596 blocks, BM=64, reg-pipelined) ----
  proj_all<<<2 * PB64 + 32, 256, 0, stream>>>(
      mashup, api, x, domain, wt0, wt1, wt2, wt3,
      bsde, bkey, bval, bsie, M0y8, y0a8, vmi, vkey, vval, dm, da, outA);

  attn_kernel<<<BATCH, 256, 0, stream>>>(vmi, vkey, vval, zm);

  // ---- bipartite LightGCN (fp8 gathers): out_api = 0.25*(A0 + P^T(M0+M1+M2)) ----
  prop_p1<<<NA / 4, 256, 0, stream>>>((const uint32_t*)M0y8, (const uint32_t*)y0a8,
                                      (uint32_t*)y01a8, adja, cnt_a, da);
  prop_p2<<<NM / 4, 256, 0, stream>>>((const uint32_t*)y01a8, (const uint32_t*)M0y8,
                                      (uint32_t*)Sy8, adjm, cnt_m, dm);
  prop_p3<<<NA / 4, 256, 0, stream>>>((const uint32_t*)Sy8, outA, Obf,
                                      adja, cnt_a, da);

  pred_mfma<<<dim3((NA + 255) / 256, BATCH / 256), 256, 0, stream>>>(zm, Obf, out);
}